// Round 4
// baseline (2714.172 us; speedup 1.0000x reference)
//
#include <hip/hip_runtime.h>
#include <stdint.h>

#define B_ 2
#define P_ 256
#define TL_ 1280
#define T_ 1536
#define H_ 1024
#define HEADS_ 16
#define HD_ 64
#define NL_ 2
#define V_ 32000
#define F_ 4096
#define BT_ (B_ * T_)

typedef __attribute__((ext_vector_type(4))) float f32x4;
typedef __attribute__((ext_vector_type(8))) short short8;
typedef __attribute__((ext_vector_type(4))) short short4v;

typedef __attribute__((address_space(3))) uint32_t lds_u32_t;
typedef const __attribute__((address_space(1))) uint32_t glb_u32_t;

__device__ inline void gload_lds16(const void* g, void* l) {
    __builtin_amdgcn_global_load_lds((glb_u32_t*)g, (lds_u32_t*)l, 16, 0, 0);
}

__device__ inline short f2bf(float f) {
    union { float f; unsigned u; } v; v.f = f;
    unsigned r = v.u + 0x7FFF + ((v.u >> 16) & 1);
    return (short)(r >> 16);
}

#define BAR() asm volatile("s_barrier" ::: "memory")
#define WAIT_VM0() asm volatile("s_waitcnt vmcnt(0)" ::: "memory")

// ---------------- fused weight transpose-convert: f32 [K,N] -> bf16 [N,K] ----
// one launch for all 13 matrices; grid = 56576 tiles of 32x32.
__global__ __launch_bounds__(256) void k_cvt_all(
    const float* __restrict__ Wq, const float* __restrict__ Wk,
    const float* __restrict__ Wv, const float* __restrict__ Wo,
    const float* __restrict__ W1, const float* __restrict__ W2,
    const float* __restrict__ Wh,
    short* __restrict__ WqkvT, short* __restrict__ WoT,
    short* __restrict__ W1T, short* __restrict__ W2T, short* __restrict__ WhT) {
    int id = blockIdx.x;
    const float* src;
    short* dst;
    int K, N;
    float scale = 1.f;
    if (id < 6144) {                       // qkv: 2 layers x 3 mats x 1024 tiles
        int mat = id >> 10;
        int tile = id & 1023;
        int l = mat / 3, which = mat - l * 3;
        src = (which == 0 ? Wq : which == 1 ? Wk : Wv) + (size_t)l * H_ * H_;
        dst = WqkvT + (size_t)(l * 3 + which) * H_ * H_;
        K = H_; N = H_;
        if (which == 0) scale = 0.125f;
        id = tile;
    } else if (id < 8192) {                // wo
        int rel = id - 6144;
        int l = rel >> 10;
        src = Wo + (size_t)l * H_ * H_;
        dst = WoT + (size_t)l * H_ * H_;
        K = H_; N = H_;
        id = rel & 1023;
    } else if (id < 16384) {               // w1: K=H, N=F
        int rel = id - 8192;
        int l = rel >> 12;
        src = W1 + (size_t)l * H_ * F_;
        dst = W1T + (size_t)l * H_ * F_;
        K = H_; N = F_;
        id = rel & 4095;
    } else if (id < 24576) {               // w2: K=F, N=H
        int rel = id - 16384;
        int l = rel >> 12;
        src = W2 + (size_t)l * F_ * H_;
        dst = W2T + (size_t)l * F_ * H_;
        K = F_; N = H_;
        id = rel & 4095;
    } else {                               // head: K=H, N=V
        id -= 24576;
        src = Wh; dst = WhT;
        K = H_; N = V_;
    }
    int ntn = N >> 5;
    int nb = (id % ntn) * 32, kb = (id / ntn) * 32;

    __shared__ float ts[32][36];
    int tid = threadIdx.x;
    int r = tid >> 3, c4 = (tid & 7) * 4;
    f32x4 v = *(const f32x4*)&src[(size_t)(kb + r) * N + nb + c4];
    *(f32x4*)&ts[r][c4] = v;
    __syncthreads();
    int wn = tid >> 3, wk4 = (tid & 7) * 4;
    short o[4];
#pragma unroll
    for (int j = 0; j < 4; ++j) o[j] = f2bf(ts[wk4 + j][wn] * scale);
    *(short4v*)&dst[(size_t)(nb + wn) * K + kb + wk4] = *(short4v*)o;
}

// ---------------- embed + concat + first layernorm ---------------------------
__global__ __launch_bounds__(256) void k_embed_ln(const float* __restrict__ prefix,
                                                  const int* __restrict__ ids,
                                                  const float* __restrict__ emb,
                                                  const float* __restrict__ g,
                                                  const float* __restrict__ b,
                                                  float* __restrict__ x,
                                                  short* __restrict__ h) {
    int r = blockIdx.x;
    int bb = r / T_, t = r % T_;
    const float* src = (t < P_) ? (prefix + (size_t)(bb * P_ + t) * H_)
                                : (emb + (size_t)ids[bb * TL_ + (t - P_)] * H_);
    int tid = threadIdx.x;
    f32x4 v = *(const f32x4*)&src[tid * 4];
    *(f32x4*)&x[(size_t)r * H_ + tid * 4] = v;
    float s = v[0] + v[1] + v[2] + v[3];
    float sq = v[0] * v[0] + v[1] * v[1] + v[2] * v[2] + v[3] * v[3];
#pragma unroll
    for (int off = 32; off; off >>= 1) {
        s += __shfl_down(s, off, 64);
        sq += __shfl_down(sq, off, 64);
    }
    __shared__ float red[10];
    int wid = tid >> 6;
    if ((tid & 63) == 0) { red[wid] = s; red[4 + wid] = sq; }
    __syncthreads();
    if (tid == 0) {
        float S = red[0] + red[1] + red[2] + red[3];
        float SQ = red[4] + red[5] + red[6] + red[7];
        float mu = S * (1.0f / H_);
        float var = SQ * (1.0f / H_) - mu * mu;
        red[8] = mu;
        red[9] = rsqrtf(var + 1e-5f);
    }
    __syncthreads();
    float mu = red[8], rstd = red[9];
    short o[4];
#pragma unroll
    for (int j = 0; j < 4; ++j)
        o[j] = f2bf((v[j] - mu) * rstd * g[tid * 4 + j] + b[tid * 4 + j]);
    *(short4v*)&h[(size_t)r * H_ + tid * 4] = *(short4v*)o;
}

// ---------------- layernorm -> bf16 ----------------
__global__ __launch_bounds__(256) void k_ln(const float* __restrict__ x,
                                            const float* __restrict__ g,
                                            const float* __restrict__ b,
                                            short* __restrict__ out) {
    int r = blockIdx.x;
    const float* xr = x + (size_t)r * H_;
    int tid = threadIdx.x;
    f32x4 v = *(const f32x4*)&xr[tid * 4];
    float s = v[0] + v[1] + v[2] + v[3];
    float sq = v[0] * v[0] + v[1] * v[1] + v[2] * v[2] + v[3] * v[3];
#pragma unroll
    for (int off = 32; off; off >>= 1) {
        s += __shfl_down(s, off, 64);
        sq += __shfl_down(sq, off, 64);
    }
    __shared__ float red[10];
    int wid = tid >> 6;
    if ((tid & 63) == 0) { red[wid] = s; red[4 + wid] = sq; }
    __syncthreads();
    if (tid == 0) {
        float S = red[0] + red[1] + red[2] + red[3];
        float SQ = red[4] + red[5] + red[6] + red[7];
        float mu = S * (1.0f / H_);
        float var = SQ * (1.0f / H_) - mu * mu;
        red[8] = mu;
        red[9] = rsqrtf(var + 1e-5f);
    }
    __syncthreads();
    float mu = red[8], rstd = red[9];
    short o[4];
#pragma unroll
    for (int j = 0; j < 4; ++j)
        o[j] = f2bf((v[j] - mu) * rstd * g[tid * 4 + j] + b[tid * 4 + j]);
    *(short4v*)&out[(size_t)r * H_ + tid * 4] = *(short4v*)o;
}

// ---------------- 128x128 GEMM, BK=32, dbuf, 1 barrier/tile, swizzled --------
// C = A(bf16[M,K]) * Bt(bf16[N,K])^T.
// STORE: 0 = f32 row-major (+resid), 1 = bf16 row-major,
//        3 = fused QKV split (q bf16 / k bf16 / vT scatter)
template <int STORE, bool HAS_BIAS, bool SILU, bool RES>
__global__ __launch_bounds__(256) void k_gemm(const short* __restrict__ A,
                                              const short* __restrict__ Bt,
                                              const float* __restrict__ bias,
                                              const float* __restrict__ resid,
                                              void* __restrict__ outp,
                                              void* __restrict__ outp2,
                                              void* __restrict__ outp3,
                                              int M, int N, int K, float alpha) {
    __shared__ short As[2][128 * 32];   // 8 KiB per buf
    __shared__ short Bs[2][128 * 32];
    int tid = threadIdx.x;
    int lane = tid & 63, w = tid >> 6;
    int wr = w >> 1, wc = w & 1;
    int nwg = gridDim.x;                 // nwg % 8 == 0 for all our grids
    int mblocks = M >> 7;
    int cpx = nwg >> 3;
    int logical = (blockIdx.x & 7) * cpx + (blockIdx.x >> 3);
    int rp = logical % mblocks, cp = logical / mblocks;
    int mbase = rp * 128, nbase = cp * 128;
    int lr = lane & 15, hi = lane >> 4;
    int lg = hi * 4;

    f32x4 acc[4][4] = {};

    // staging: thread covers LDS 16B slots tid and tid+256 (rows r0, r0+64)
    int r0 = tid >> 2;
    int gcol = ((tid & 3) ^ (r0 & 3)) * 8;          // inverse-swizzled source col
    const short* Ab = A + (size_t)mbase * K;
    const short* Bb = Bt + (size_t)nbase * K;

    // fragment read byte offsets: row*64 + swizzled k-slot
    int koff = ((hi ^ (lr & 3)) << 4);
    int arow[4], brow[4];
#pragma unroll
    for (int m = 0; m < 4; ++m) arow[m] = (wr * 64 + m * 16 + lr) * 64;
#pragma unroll
    for (int n = 0; n < 4; ++n) brow[n] = (wc * 64 + n * 16 + lr) * 64;

    auto stage = [&](int t) {
        const short* ga = Ab + (size_t)r0 * K + t * 32 + gcol;
        const short* gb = Bb + (size_t)r0 * K + t * 32 + gcol;
        char* la = (char*)&As[t & 1][0];
        char* lb = (char*)&Bs[t & 1][0];
        gload_lds16(ga, la + tid * 16);
        gload_lds16(ga + (size_t)64 * K, la + tid * 16 + 4096);
        gload_lds16(gb, lb + tid * 16);
        gload_lds16(gb + (size_t)64 * K, lb + tid * 16 + 4096);
    };

    int NT = K >> 5;
    stage(0);
    WAIT_VM0();
    BAR();

    for (int t = 0; t < NT; ++t) {
        if (t + 1 < NT) stage(t + 1);
        const char* a = (const char*)&As[t & 1][0];
        const char* b = (const char*)&Bs[t & 1][0];
        short8 af[4], bfr[4];
#pragma unroll
        for (int mi = 0; mi < 4; ++mi) af[mi] = *(const short8*)(a + arow[mi] + koff);
#pragma unroll
        for (int ni = 0; ni < 4; ++ni) bfr[ni] = *(const short8*)(b + brow[ni] + koff);
        __builtin_amdgcn_s_setprio(1);
#pragma unroll
        for (int mi = 0; mi < 4; ++mi)
#pragma unroll
            for (int ni = 0; ni < 4; ++ni)
                acc[mi][ni] = __builtin_amdgcn_mfma_f32_16x16x32_bf16(af[mi], bfr[ni], acc[mi][ni], 0, 0, 0);
        __builtin_amdgcn_s_setprio(0);
        WAIT_VM0();
        BAR();
    }

#pragma unroll
    for (int ni = 0; ni < 4; ++ni) {
        int col = nbase + wc * 64 + ni * 16 + lr;
        float bv = HAS_BIAS ? bias[col] : 0.f;
#pragma unroll
        for (int mi = 0; mi < 4; ++mi) {
#pragma unroll
            for (int j = 0; j < 4; ++j) {
                int row = mbase + wr * 64 + mi * 16 + lg + j;
                float vv = acc[mi][ni][j] * alpha + bv;
                if (SILU) vv = vv / (1.f + __expf(-vv));
                if (RES) vv += resid[(size_t)row * N + col];
                if (STORE == 0) {
                    ((float*)outp)[(size_t)row * N + col] = vv;
                } else if (STORE == 1) {
                    ((short*)outp)[(size_t)row * N + col] = f2bf(vv);
                } else {  // STORE == 3: fused QKV
                    int seg = col >> 10;
                    int c = col & 1023;
                    if (seg == 0) {
                        ((short*)outp)[(size_t)row * H_ + c] = f2bf(vv);
                    } else if (seg == 1) {
                        ((short*)outp2)[(size_t)row * H_ + c] = f2bf(vv);
                    } else {
                        int bb = row / T_, t2 = row % T_;
                        ((short*)outp3)[((size_t)(bb * HEADS_ + (c >> 6)) * HD_ + (c & 63)) * T_ + t2] = f2bf(vv);
                    }
                }
            }
        }
    }
}

// ---------------- 256x256 GEMM, BK=32, dbuf (64 KiB), 2 blocks/CU ------------
// C = A(bf16[M,K]) * Bt(bf16[N,K])^T, f32 out. M%256==0, N%256==0, K%32==0.
__global__ __launch_bounds__(512, 4) void k_gemm8(const short* __restrict__ A,
                                                  const short* __restrict__ Bt,
                                                  float* __restrict__ C,
                                                  int M, int N, int K) {
    __shared__ short As[2][256 * 32];   // 16 KiB per buf
    __shared__ short Bs[2][256 * 32];
    int tid = threadIdx.x;
    int lane = tid & 63, w = tid >> 6;
    int wr = w >> 2, wc = w & 3;         // 2 x 4 waves; wave owns 128x64 of C
    int lr = lane & 15, hi = lane >> 4;

    // bijective XCD swizzle (m204 form)
    int mtiles = M >> 8;
    int nwg = gridDim.x;
    int q = nwg >> 3, r = nwg & 7;
    int xcd = blockIdx.x & 7, lid = blockIdx.x >> 3;
    int wgid = (xcd < r ? xcd * (q + 1) : r * (q + 1) + (xcd - r) * q) + lid;
    int rp = wgid % mtiles, cp = wgid / mtiles;   // M-major: B-panel L2 reuse

    const short* Ab = A + (size_t)rp * 256 * K;
    const short* Bb = Bt + (size_t)cp * 256 * K;

    // staging: thread covers LDS 16B slots tid and tid+512 (rows r0, r0+128)
    int r0 = tid >> 2;
    int gcol = ((tid & 3) ^ (r0 & 3)) * 8;
    // fragment reads: byte addr = row*64 + swizzled slot
    int koff = ((hi ^ (lr & 3)) << 4);
    int arow[8], brow[4];
#pragma unroll
    for (int m = 0; m < 8; ++m) arow[m] = (wr * 128 + m * 16 + lr) * 64;
#pragma unroll
    for (int n = 0; n < 4; ++n) brow[n] = (wc * 64 + n * 16 + lr) * 64;

    f32x4 acc[8][4] = {};

    auto stage = [&](int t) {
        const short* ga = Ab + (size_t)r0 * K + t * 32 + gcol;
        const short* gb = Bb + (size_t)r0 * K + t * 32 + gcol;
        char* la = (char*)&As[t & 1][0];
        char* lb = (char*)&Bs[t & 1][0];
        gload_lds16(ga, la + tid * 16);
        gload_lds16(ga + (size_t)128 * K, la + tid * 16 + 8192);
        gload_lds16(gb, lb + tid * 16);
        gload_lds16(gb + (size_t)128 * K, lb + tid * 16 + 8192);
    };

    int NT = K >> 5;
    stage(0);
    WAIT_VM0();
    BAR();

    for (int t = 0; t < NT; ++t) {
        if (t + 1 < NT) stage(t + 1);
        const char* a = (const char*)&As[t & 1][0];
        const char* b = (const char*)&Bs[t & 1][0];
        short8 aF[4], bF[4], aG[4];
#pragma unroll
        for (int m = 0; m < 4; ++m) aF[m] = *(const short8*)(a + arow[m] + koff);
#pragma unroll
        for (int n = 0; n < 4; ++n) bF[n] = *(const short8*)(b + brow[n] + koff);
        __builtin_amdgcn_s_setprio(1);
#pragma unroll
        for (int m = 0; m < 4; ++m)
#pragma unroll
            for (int n = 0; n < 4; ++n)
                acc[m][n] = __builtin_amdgcn_mfma_f32_16x16x32_bf16(aF[m], bF[n], acc[m][n], 0, 0, 0);
        __builtin_amdgcn_s_setprio(0);
#pragma unroll
        for (int m = 0; m < 4; ++m) aG[m] = *(const short8*)(a + arow[4 + m] + koff);
        __builtin_amdgcn_s_setprio(1);
#pragma unroll
        for (int m = 0; m < 4; ++m)
#pragma unroll
            for (int n = 0; n < 4; ++n)
                acc[4 + m][n] = __builtin_amdgcn_mfma_f32_16x16x32_bf16(aG[m], bF[n], acc[4 + m][n], 0, 0, 0);
        __builtin_amdgcn_s_setprio(0);
        WAIT_VM0();
        BAR();
    }

    int crow = rp * 256 + wr * 128 + hi * 4;
    int ccol = cp * 256 + wc * 64 + lr;
#pragma unroll
    for (int m = 0; m < 8; ++m)
#pragma unroll
        for (int n = 0; n < 4; ++n) {
#pragma unroll
            for (int j = 0; j < 4; ++j)
                C[(size_t)(crow + m * 16 + j) * N + ccol + n * 16] = acc[m][n][j];
        }
}

// ---------------- flash attention ----------------
__global__ __launch_bounds__(256) void k_attn(const short* __restrict__ q,
                                              const short* __restrict__ k,
                                              const short* __restrict__ vT,
                                              short* __restrict__ out) {
    int qt = blockIdx.x, head = blockIdx.y, b = blockIdx.z;
    int qbase = qt * 64;
    __shared__ short Qs[64][72];
    __shared__ short Ps[4][16][72];
    int tid = threadIdx.x, lane = tid & 63, w = tid >> 6;
    int lr = lane & 15, lg4 = (lane >> 4) * 4, lk8 = (lane >> 4) * 8;

#pragma unroll
    for (int c = 0; c < 2; ++c) {
        int chunk = tid + 256 * c;
        int row = chunk >> 3, h8 = (chunk & 7) * 8;
        *(short8*)&Qs[row][h8] =
            *(const short8*)&q[(size_t)(b * T_ + qbase + row) * H_ + head * HD_ + h8];
    }
    __syncthreads();

    short8 qf[2];
    qf[0] = *(short8*)&Qs[w * 16 + lr][lk8];
    qf[1] = *(short8*)&Qs[w * 16 + lr][32 + lk8];

    f32x4 o[4] = {};
    float m[4] = {-1e30f, -1e30f, -1e30f, -1e30f};
    float lsum[4] = {0.f, 0.f, 0.f, 0.f};

    for (int kt = 0; kt <= qt; ++kt) {
        int kb = kt * 64;
        f32x4 s[4] = {};
#pragma unroll
        for (int ks = 0; ks < 2; ++ks) {
#pragma unroll
            for (int f = 0; f < 4; ++f) {
                short8 kf = *(const short8*)&k[(size_t)(b * T_ + kb + f * 16 + lr) * H_ +
                                               head * HD_ + ks * 32 + lk8];
                s[f] = __builtin_amdgcn_mfma_f32_16x16x32_bf16(qf[ks], kf, s[f], 0, 0, 0);
            }
        }
        if (kt == qt) {
#pragma unroll
            for (int f = 0; f < 4; ++f) {
                int key = kb + f * 16 + lr;
#pragma unroll
                for (int j = 0; j < 4; ++j) {
                    int qrow = qbase + w * 16 + lg4 + j;
                    if (key > qrow) s[f][j] = -1e30f;
                }
            }
        }
#pragma unroll
        for (int j = 0; j < 4; ++j) {
            float mx = fmaxf(fmaxf(s[0][j], s[1][j]), fmaxf(s[2][j], s[3][j]));
#pragma unroll
            for (int off = 1; off < 16; off <<= 1) mx = fmaxf(mx, __shfl_xor(mx, off, 64));
            float mnew = fmaxf(m[j], mx);
            float sc = __expf(m[j] - mnew);
            m[j] = mnew;
            float rs = 0.f;
#pragma unroll
            for (int f = 0; f < 4; ++f) {
                float p = __expf(s[f][j] - mnew);
                s[f][j] = p;
                rs += p;
            }
#pragma unroll
            for (int off = 1; off < 16; off <<= 1) rs += __shfl_xor(rs, off, 64);
            lsum[j] = lsum[j] * sc + rs;
#pragma unroll
            for (int f = 0; f < 4; ++f) o[f][j] *= sc;
#pragma unroll
            for (int f = 0; f < 4; ++f) Ps[w][lg4 + j][f * 16 + lr] = f2bf(s[f][j]);
        }
#pragma unroll
        for (int ks2 = 0; ks2 < 2; ++ks2) {
            short8 pf = *(short8*)&Ps[w][lr][ks2 * 32 + lk8];
#pragma unroll
            for (int f = 0; f < 4; ++f) {
                short8 vf = *(const short8*)&vT[((size_t)(b * HEADS_ + head) * HD_ + f * 16 + lr) * T_ +
                                                kb + ks2 * 32 + lk8];
                o[f] = __builtin_amdgcn_mfma_f32_16x16x32_bf16(pf, vf, o[f], 0, 0, 0);
            }
        }
    }
#pragma unroll
    for (int f = 0; f < 4; ++f)
#pragma unroll
        for (int j = 0; j < 4; ++j) {
            float val = o[f][j] / lsum[j];
            out[(size_t)(b * T_ + qbase + w * 16 + lg4 + j) * H_ + head * HD_ + f * 16 + lr] =
                f2bf(val);
        }
}

// ---------------- launch ----------------
extern "C" void kernel_launch(void* const* d_in, const int* in_sizes, int n_in,
                              void* d_out, int out_size, void* d_ws, size_t ws_size,
                              hipStream_t stream) {
    const float* prefix = (const float*)d_in[0];
    const int* ids = (const int*)d_in[1];
    const float* emb = (const float*)d_in[2];
    const float* Wq = (const float*)d_in[3];
    const float* Wk = (const float*)d_in[4];
    const float* Wv = (const float*)d_in[5];
    const float* Wo = (const float*)d_in[6];
    const float* g1 = (const float*)d_in[7];
    const float* b1 = (const float*)d_in[8];
    const float* g2 = (const float*)d_in[9];
    const float* b2 = (const float*)d_in[10];
    const float* W1 = (const float*)d_in[11];
    const float* bm1 = (const float*)d_in[12];
    const float* W2 = (const float*)d_in[13];
    const float* bm2 = (const float*)d_in[14];
    const float* gf = (const float*)d_in[15];
    const float* bf = (const float*)d_in[16];
    const float* Whead = (const float*)d_in[17];
    float* out = (float*)d_out;

    char* wsp = (char*)d_ws;
    float* x = (float*)wsp;   wsp += (size_t)BT_ * H_ * 4;
    short* h = (short*)wsp;   wsp += (size_t)BT_ * H_ * 2;
    short* qb = (short*)wsp;  wsp += (size_t)BT_ * H_ * 2;
    short* kb = (short*)wsp;  wsp += (size_t)BT_ * H_ * 2;
    short* vT = (short*)wsp;  wsp += (size_t)BT_ * H_ * 2;
    short* ao = (short*)wsp;  wsp += (size_t)BT_ * H_ * 2;
    short* mid = (short*)wsp; wsp += (size_t)BT_ * F_ * 2;
    short* WqkvT = (short*)wsp; wsp += (size_t)NL_ * 3 * H_ * H_ * 2;
    short* WoT = (short*)wsp;   wsp += (size_t)NL_ * H_ * H_ * 2;
    short* W1T = (short*)wsp;   wsp += (size_t)NL_ * H_ * F_ * 2;
    short* W2T = (short*)wsp;   wsp += (size_t)NL_ * F_ * H_ * 2;
    short* WhT = (short*)wsp;   wsp += (size_t)H_ * V_ * 2;

    dim3 blk(256);
    k_cvt_all<<<dim3(56576), blk, 0, stream>>>(Wq, Wk, Wv, Wo, W1, W2, Whead,
                                               WqkvT, WoT, W1T, W2T, WhT);
    k_embed_ln<<<BT_, blk, 0, stream>>>(prefix, ids, emb, g1, b1, x, h);
    for (int l = 0; l < NL_; ++l) {
        size_t o1 = (size_t)l * H_ * H_;
        size_t oq = (size_t)l * 3 * H_ * H_;
        size_t o2 = (size_t)l * H_ * F_;
        k_gemm<3, false, false, false><<<dim3(576), blk, 0, stream>>>(
            h, WqkvT + oq, nullptr, nullptr, qb, kb, vT, BT_, 3 * H_, H_, 1.f);
        k_attn<<<dim3(T_ / 64, HEADS_, B_), blk, 0, stream>>>(qb, kb, vT, ao);
        k_gemm<0, false, false, true><<<dim3(192), blk, 0, stream>>>(
            ao, WoT + o1, nullptr, x, x, nullptr, nullptr, BT_, H_, H_, 1.f);
        k_ln<<<BT_, blk, 0, stream>>>(x, g2 + l * H_, b2 + l * H_, h);
        k_gemm<1, true, true, false><<<dim3(768), blk, 0, stream>>>(
            h, W1T + o2, bm1 + (size_t)l * F_, nullptr, mid, nullptr, nullptr, BT_, F_, H_, 1.f);
        k_gemm<0, true, false, true><<<dim3(192), blk, 0, stream>>>(
            mid, W2T + o2, bm2 + (size_t)l * H_, x, x, nullptr, nullptr, BT_, H_, F_, 1.f);
        // layernorm feeding next layer's QKV (or the head)
        const float* gn = (l + 1 < NL_) ? g1 + (l + 1) * H_ : gf;
        const float* bn = (l + 1 < NL_) ? b1 + (l + 1) * H_ : bf;
        k_ln<<<BT_, blk, 0, stream>>>(x, gn, bn, h);
    }
    k_gemm8<<<dim3((BT_ / 256) * (V_ / 256)), dim3(512), 0, stream>>>(
        h, WhT, out, BT_, V_, H_);
}

// Round 5
// 1067.025 us; speedup vs baseline: 2.5437x; 2.5437x over previous
//
#include <hip/hip_runtime.h>
#include <stdint.h>

#define B_ 2
#define P_ 256
#define TL_ 1280
#define T_ 1536
#define H_ 1024
#define HEADS_ 16
#define HD_ 64
#define NL_ 2
#define V_ 32000
#define F_ 4096
#define BT_ (B_ * T_)

typedef __attribute__((ext_vector_type(4))) float f32x4;
typedef __attribute__((ext_vector_type(8))) short short8;
typedef __attribute__((ext_vector_type(4))) short short4v;

typedef __attribute__((address_space(3))) uint32_t lds_u32_t;
typedef const __attribute__((address_space(1))) uint32_t glb_u32_t;

__device__ inline void gload_lds16(const void* g, void* l) {
    __builtin_amdgcn_global_load_lds((glb_u32_t*)g, (lds_u32_t*)l, 16, 0, 0);
}

__device__ inline short f2bf(float f) {
    union { float f; unsigned u; } v; v.f = f;
    unsigned r = v.u + 0x7FFF + ((v.u >> 16) & 1);
    return (short)(r >> 16);
}

#define BAR() asm volatile("s_barrier" ::: "memory")
#define WAIT_VM0() asm volatile("s_waitcnt vmcnt(0)" ::: "memory")

// ---------------- fused weight transpose-convert: f32 [K,N] -> bf16 [N,K] ----
__global__ __launch_bounds__(256) void k_cvt_all(
    const float* __restrict__ Wq, const float* __restrict__ Wk,
    const float* __restrict__ Wv, const float* __restrict__ Wo,
    const float* __restrict__ W1, const float* __restrict__ W2,
    const float* __restrict__ Wh,
    short* __restrict__ WqkvT, short* __restrict__ WoT,
    short* __restrict__ W1T, short* __restrict__ W2T, short* __restrict__ WhT) {
    int id = blockIdx.x;
    const float* src;
    short* dst;
    int K, N;
    float scale = 1.f;
    if (id < 6144) {                       // qkv: 2 layers x 3 mats x 1024 tiles
        int mat = id >> 10;
        int tile = id & 1023;
        int l = mat / 3, which = mat - l * 3;
        src = (which == 0 ? Wq : which == 1 ? Wk : Wv) + (size_t)l * H_ * H_;
        dst = WqkvT + (size_t)(l * 3 + which) * H_ * H_;
        K = H_; N = H_;
        if (which == 0) scale = 0.125f;
        id = tile;
    } else if (id < 8192) {                // wo
        int rel = id - 6144;
        int l = rel >> 10;
        src = Wo + (size_t)l * H_ * H_;
        dst = WoT + (size_t)l * H_ * H_;
        K = H_; N = H_;
        id = rel & 1023;
    } else if (id < 16384) {               // w1: K=H, N=F
        int rel = id - 8192;
        int l = rel >> 12;
        src = W1 + (size_t)l * H_ * F_;
        dst = W1T + (size_t)l * H_ * F_;
        K = H_; N = F_;
        id = rel & 4095;
    } else if (id < 24576) {               // w2: K=F, N=H
        int rel = id - 16384;
        int l = rel >> 12;
        src = W2 + (size_t)l * F_ * H_;
        dst = W2T + (size_t)l * F_ * H_;
        K = F_; N = H_;
        id = rel & 4095;
    } else {                               // head: K=H, N=V
        id -= 24576;
        src = Wh; dst = WhT;
        K = H_; N = V_;
    }
    int ntn = N >> 5;
    int nb = (id % ntn) * 32, kb = (id / ntn) * 32;

    __shared__ float ts[32][36];
    int tid = threadIdx.x;
    int r = tid >> 3, c4 = (tid & 7) * 4;
    f32x4 v = *(const f32x4*)&src[(size_t)(kb + r) * N + nb + c4];
    *(f32x4*)&ts[r][c4] = v;
    __syncthreads();
    int wn = tid >> 3, wk4 = (tid & 7) * 4;
    short o[4];
#pragma unroll
    for (int j = 0; j < 4; ++j) o[j] = f2bf(ts[wk4 + j][wn] * scale);
    *(short4v*)&dst[(size_t)(nb + wn) * K + kb + wk4] = *(short4v*)o;
}

// ---------------- embed + concat + first layernorm ---------------------------
__global__ __launch_bounds__(256) void k_embed_ln(const float* __restrict__ prefix,
                                                  const int* __restrict__ ids,
                                                  const float* __restrict__ emb,
                                                  const float* __restrict__ g,
                                                  const float* __restrict__ b,
                                                  float* __restrict__ x,
                                                  short* __restrict__ h) {
    int r = blockIdx.x;
    int bb = r / T_, t = r % T_;
    const float* src = (t < P_) ? (prefix + (size_t)(bb * P_ + t) * H_)
                                : (emb + (size_t)ids[bb * TL_ + (t - P_)] * H_);
    int tid = threadIdx.x;
    f32x4 v = *(const f32x4*)&src[tid * 4];
    *(f32x4*)&x[(size_t)r * H_ + tid * 4] = v;
    float s = v[0] + v[1] + v[2] + v[3];
    float sq = v[0] * v[0] + v[1] * v[1] + v[2] * v[2] + v[3] * v[3];
#pragma unroll
    for (int off = 32; off; off >>= 1) {
        s += __shfl_down(s, off, 64);
        sq += __shfl_down(sq, off, 64);
    }
    __shared__ float red[10];
    int wid = tid >> 6;
    if ((tid & 63) == 0) { red[wid] = s; red[4 + wid] = sq; }
    __syncthreads();
    if (tid == 0) {
        float S = red[0] + red[1] + red[2] + red[3];
        float SQ = red[4] + red[5] + red[6] + red[7];
        float mu = S * (1.0f / H_);
        float var = SQ * (1.0f / H_) - mu * mu;
        red[8] = mu;
        red[9] = rsqrtf(var + 1e-5f);
    }
    __syncthreads();
    float mu = red[8], rstd = red[9];
    short o[4];
#pragma unroll
    for (int j = 0; j < 4; ++j)
        o[j] = f2bf((v[j] - mu) * rstd * g[tid * 4 + j] + b[tid * 4 + j]);
    *(short4v*)&h[(size_t)r * H_ + tid * 4] = *(short4v*)o;
}

// ---------------- layernorm -> bf16 ----------------
__global__ __launch_bounds__(256) void k_ln(const float* __restrict__ x,
                                            const float* __restrict__ g,
                                            const float* __restrict__ b,
                                            short* __restrict__ out) {
    int r = blockIdx.x;
    const float* xr = x + (size_t)r * H_;
    int tid = threadIdx.x;
    f32x4 v = *(const f32x4*)&xr[tid * 4];
    float s = v[0] + v[1] + v[2] + v[3];
    float sq = v[0] * v[0] + v[1] * v[1] + v[2] * v[2] + v[3] * v[3];
#pragma unroll
    for (int off = 32; off; off >>= 1) {
        s += __shfl_down(s, off, 64);
        sq += __shfl_down(sq, off, 64);
    }
    __shared__ float red[10];
    int wid = tid >> 6;
    if ((tid & 63) == 0) { red[wid] = s; red[4 + wid] = sq; }
    __syncthreads();
    if (tid == 0) {
        float S = red[0] + red[1] + red[2] + red[3];
        float SQ = red[4] + red[5] + red[6] + red[7];
        float mu = S * (1.0f / H_);
        float var = SQ * (1.0f / H_) - mu * mu;
        red[8] = mu;
        red[9] = rsqrtf(var + 1e-5f);
    }
    __syncthreads();
    float mu = red[8], rstd = red[9];
    short o[4];
#pragma unroll
    for (int j = 0; j < 4; ++j)
        o[j] = f2bf((v[j] - mu) * rstd * g[tid * 4 + j] + b[tid * 4 + j]);
    *(short4v*)&out[(size_t)r * H_ + tid * 4] = *(short4v*)o;
}

// ---------------- 128x128 GEMM, BK=32, dbuf, 1 barrier/tile, swizzled --------
// C = A(bf16[M,K]) * Bt(bf16[N,K])^T.
// STORE: 0 = f32 row-major (+resid), 1 = bf16 row-major,
//        3 = fused QKV split (q bf16 / k bf16 / vT scatter)
template <int STORE, bool HAS_BIAS, bool SILU, bool RES>
__global__ __launch_bounds__(256) void k_gemm(const short* __restrict__ A,
                                              const short* __restrict__ Bt,
                                              const float* __restrict__ bias,
                                              const float* __restrict__ resid,
                                              void* __restrict__ outp,
                                              void* __restrict__ outp2,
                                              void* __restrict__ outp3,
                                              int M, int N, int K, float alpha) {
    __shared__ short As[2][128 * 32];   // 8 KiB per buf
    __shared__ short Bs[2][128 * 32];
    int tid = threadIdx.x;
    int lane = tid & 63, w = tid >> 6;
    int wr = w >> 1, wc = w & 1;
    int nwg = gridDim.x;                 // nwg % 8 == 0 for all our grids
    int mblocks = M >> 7;
    int cpx = nwg >> 3;
    int logical = (blockIdx.x & 7) * cpx + (blockIdx.x >> 3);
    int rp = logical % mblocks, cp = logical / mblocks;
    int mbase = rp * 128, nbase = cp * 128;
    int lr = lane & 15, hi = lane >> 4;
    int lg = hi * 4;

    f32x4 acc[4][4] = {};

    // staging: thread covers LDS 16B slots tid and tid+256 (rows r0, r0+64)
    int r0 = tid >> 2;
    int gcol = ((tid & 3) ^ (r0 & 3)) * 8;          // inverse-swizzled source col
    const short* Ab = A + (size_t)mbase * K;
    const short* Bb = Bt + (size_t)nbase * K;

    // fragment read byte offsets: row*64 + swizzled k-slot
    int koff = ((hi ^ (lr & 3)) << 4);
    int arow[4], brow[4];
#pragma unroll
    for (int m = 0; m < 4; ++m) arow[m] = (wr * 64 + m * 16 + lr) * 64;
#pragma unroll
    for (int n = 0; n < 4; ++n) brow[n] = (wc * 64 + n * 16 + lr) * 64;

    auto stage = [&](int t) {
        const short* ga = Ab + (size_t)r0 * K + t * 32 + gcol;
        const short* gb = Bb + (size_t)r0 * K + t * 32 + gcol;
        char* la = (char*)&As[t & 1][0];
        char* lb = (char*)&Bs[t & 1][0];
        gload_lds16(ga, la + tid * 16);
        gload_lds16(ga + (size_t)64 * K, la + tid * 16 + 4096);
        gload_lds16(gb, lb + tid * 16);
        gload_lds16(gb + (size_t)64 * K, lb + tid * 16 + 4096);
    };

    int NT = K >> 5;
    stage(0);
    WAIT_VM0();
    BAR();

    for (int t = 0; t < NT; ++t) {
        if (t + 1 < NT) stage(t + 1);
        const char* a = (const char*)&As[t & 1][0];
        const char* b = (const char*)&Bs[t & 1][0];
        short8 af[4], bfr[4];
#pragma unroll
        for (int mi = 0; mi < 4; ++mi) af[mi] = *(const short8*)(a + arow[mi] + koff);
#pragma unroll
        for (int ni = 0; ni < 4; ++ni) bfr[ni] = *(const short8*)(b + brow[ni] + koff);
        __builtin_amdgcn_s_setprio(1);
#pragma unroll
        for (int mi = 0; mi < 4; ++mi)
#pragma unroll
            for (int ni = 0; ni < 4; ++ni)
                acc[mi][ni] = __builtin_amdgcn_mfma_f32_16x16x32_bf16(af[mi], bfr[ni], acc[mi][ni], 0, 0, 0);
        __builtin_amdgcn_s_setprio(0);
        WAIT_VM0();
        BAR();
    }

#pragma unroll
    for (int ni = 0; ni < 4; ++ni) {
        int col = nbase + wc * 64 + ni * 16 + lr;
        float bv = HAS_BIAS ? bias[col] : 0.f;
#pragma unroll
        for (int mi = 0; mi < 4; ++mi) {
#pragma unroll
            for (int j = 0; j < 4; ++j) {
                int row = mbase + wr * 64 + mi * 16 + lg + j;
                float vv = acc[mi][ni][j] * alpha + bv;
                if (SILU) vv = vv / (1.f + __expf(-vv));
                if (RES) vv += resid[(size_t)row * N + col];
                if (STORE == 0) {
                    ((float*)outp)[(size_t)row * N + col] = vv;
                } else if (STORE == 1) {
                    ((short*)outp)[(size_t)row * N + col] = f2bf(vv);
                } else {  // STORE == 3: fused QKV
                    int seg = col >> 10;
                    int c = col & 1023;
                    if (seg == 0) {
                        ((short*)outp)[(size_t)row * H_ + c] = f2bf(vv);
                    } else if (seg == 1) {
                        ((short*)outp2)[(size_t)row * H_ + c] = f2bf(vv);
                    } else {
                        int bb = row / T_, t2 = row % T_;
                        ((short*)outp3)[((size_t)(bb * HEADS_ + (c >> 6)) * HD_ + (c & 63)) * T_ + t2] = f2bf(vv);
                    }
                }
            }
        }
    }
}

// ---------------- 8-phase 256x256 GEMM (T2+T3+T4+T5), f32 output -------------
// Round-2 version (verified 257 us / 783 TF): 1 block/CU by design; intra-block
// phase overlap feeds the pipe. DO NOT cap registers below 256/wave — the
// accumulator needs ~128 VGPRs and capping forces scratch spills (round-3
// post-mortem: VGPR 120->64, 9.5 GB scratch traffic, 7.5x slowdown).
__global__ __launch_bounds__(512, 2) void k_gemm8(const short* __restrict__ A,
                                                  const short* __restrict__ Bt,
                                                  float* __restrict__ C,
                                                  int M, int N, int K) {
    __shared__ short As[2 * 256 * 64];   // 64 KiB
    __shared__ short Bs[2 * 256 * 64];   // 64 KiB
    int tid = threadIdx.x;
    int lane = tid & 63, w = tid >> 6;
    int wr = w >> 2, wc = w & 3;         // 2 x 4 waves; wave owns 128x64 of C
    int lr = lane & 15, hi = lane >> 4;

    // bijective XCD swizzle (m204 form; works for any nwg)
    int mtiles = M >> 8;
    int nwg = gridDim.x;
    int q = nwg >> 3, r = nwg & 7;
    int xcd = blockIdx.x & 7, lid = blockIdx.x >> 3;
    int wgid = (xcd < r ? xcd * (q + 1) : r * (q + 1) + (xcd - r) * q) + lid;
    int rp = wgid % mtiles, cp = wgid / mtiles;   // M-major: B-panel reuse in L2

    const short* Ab = A + (size_t)rp * 256 * K;
    const short* Bb = Bt + (size_t)cp * 256 * K;

    int r0 = tid >> 3;                              // row within half (load 0)
    int gcol = ((tid & 7) ^ (r0 & 7)) * 8;          // bf16 col within 64-k tile

    int koff0 = (hi * 16) ^ ((lr & 7) << 4);
    int koff1 = (64 + hi * 16) ^ ((lr & 7) << 4);
    int arow[8], brow[4];
#pragma unroll
    for (int m = 0; m < 8; ++m) arow[m] = (wr * 128 + m * 16 + lr) * 128;
#pragma unroll
    for (int n = 0; n < 4; ++n) brow[n] = (wc * 64 + n * 16 + lr) * 128;

    f32x4 acc[8][4] = {};
    short8 aF[4][2], bF[4][2];
    const char* Ac = (const char*)As;
    const char* Bc = (const char*)Bs;

    auto stage = [&](const short* Gb, char* Lb, int tau, int hf) {
        const short* g0 = Gb + (size_t)(hf * 128 + r0) * K + tau * 64 + gcol;
        char* l = Lb + (tau & 1) * 32768 + hf * 16384;
        gload_lds16(g0, l + tid * 16);
        gload_lds16(g0 + (size_t)64 * K, l + (tid + 512) * 16);
    };
    auto lda4 = [&](const char* base, int roff) {
#pragma unroll
        for (int m = 0; m < 4; ++m) {
            aF[m][0] = *(const short8*)(base + arow[roff + m] + koff0);
            aF[m][1] = *(const short8*)(base + arow[roff + m] + koff1);
        }
    };
    auto ldb2 = [&](const char* base, int noff) {
#pragma unroll
        for (int n = 0; n < 2; ++n) {
            bF[noff + n][0] = *(const short8*)(base + brow[noff + n] + koff0);
            bF[noff + n][1] = *(const short8*)(base + brow[noff + n] + koff1);
        }
    };

#define MFMA_QUAD(MOFF, NOFF)                                                          \
    __builtin_amdgcn_s_setprio(1);                                                     \
    _Pragma("unroll") for (int m = 0; m < 4; ++m) {                                    \
        _Pragma("unroll") for (int n = 0; n < 2; ++n) {                                \
            acc[MOFF + m][NOFF + n] = __builtin_amdgcn_mfma_f32_16x16x32_bf16(         \
                aF[m][0], bF[NOFF + n][0], acc[MOFF + m][NOFF + n], 0, 0, 0);          \
            acc[MOFF + m][NOFF + n] = __builtin_amdgcn_mfma_f32_16x16x32_bf16(         \
                aF[m][1], bF[NOFF + n][1], acc[MOFF + m][NOFF + n], 0, 0, 0);          \
        }                                                                              \
    }                                                                                  \
    __builtin_amdgcn_s_setprio(0);

    int NK = K >> 6;
    stage(Ab, (char*)As, 0, 0); stage(Ab, (char*)As, 0, 1);
    stage(Bb, (char*)Bs, 0, 0); stage(Bb, (char*)Bs, 0, 1);
    stage(Ab, (char*)As, 1, 0); stage(Ab, (char*)As, 1, 1);
    stage(Bb, (char*)Bs, 1, 0); stage(Bb, (char*)Bs, 1, 1);
    asm volatile("s_waitcnt vmcnt(0)" ::: "memory");
    BAR();

    int niters = NK >> 1;
    for (int it = 0; it < niters; ++it) {
        bool st = it < niters - 1;
        int u2 = 2 * it + 2, v2 = 2 * it + 3;
        const char* a0 = Ac;            const char* b0 = Bc;
        const char* a1 = Ac + 32768;    const char* b1 = Bc + 32768;

        // ===== tile u (buf0), phases 1-4 =====
        lda4(a0, 0); ldb2(b0, 0);
        BAR();
        MFMA_QUAD(0, 0);
        BAR();
        ldb2(b0, 2);
        BAR();
        MFMA_QUAD(0, 2);
        BAR();
        lda4(a0, 4);
        if (st) stage(Bb, (char*)Bs, u2, 0);
        BAR();
        MFMA_QUAD(4, 0);
        BAR();
        if (st) stage(Bb, (char*)Bs, u2, 1);
        BAR();
        MFMA_QUAD(4, 2);
        asm volatile("s_waitcnt vmcnt(4)" ::: "memory");
        BAR();

        // ===== tile v (buf1), phases 5-8 =====
        lda4(a1, 0); ldb2(b1, 0);
        if (st) stage(Ab, (char*)As, u2, 0);
        BAR();
        MFMA_QUAD(0, 0);
        BAR();
        ldb2(b1, 2);
        if (st) stage(Ab, (char*)As, u2, 1);
        BAR();
        MFMA_QUAD(0, 2);
        BAR();
        lda4(a1, 4);
        if (st) stage(Bb, (char*)Bs, v2, 0);
        BAR();
        MFMA_QUAD(4, 0);
        BAR();
        if (st) { stage(Bb, (char*)Bs, v2, 1); stage(Ab, (char*)As, v2, 0); stage(Ab, (char*)As, v2, 1); }
        BAR();
        MFMA_QUAD(4, 2);
        asm volatile("s_waitcnt vmcnt(8)" ::: "memory");
        BAR();
    }

    int crow = rp * 256 + wr * 128 + hi * 4;
    int ccol = cp * 256 + wc * 64 + lr;
#pragma unroll
    for (int m = 0; m < 8; ++m)
#pragma unroll
        for (int n = 0; n < 4; ++n) {
#pragma unroll
            for (int j = 0; j < 4; ++j)
                C[(size_t)(crow + m * 16 + j) * N + ccol + n * 16] = acc[m][n][j];
        }
#undef MFMA_QUAD
}

// ---------------- flash attention ----------------
__global__ __launch_bounds__(256) void k_attn(const short* __restrict__ q,
                                              const short* __restrict__ k,
                                              const short* __restrict__ vT,
                                              short* __restrict__ out) {
    int qt = blockIdx.x, head = blockIdx.y, b = blockIdx.z;
    int qbase = qt * 64;
    __shared__ short Qs[64][72];
    __shared__ short Ps[4][16][72];
    int tid = threadIdx.x, lane = tid & 63, w = tid >> 6;
    int lr = lane & 15, lg4 = (lane >> 4) * 4, lk8 = (lane >> 4) * 8;

#pragma unroll
    for (int c = 0; c < 2; ++c) {
        int chunk = tid + 256 * c;
        int row = chunk >> 3, h8 = (chunk & 7) * 8;
        *(short8*)&Qs[row][h8] =
            *(const short8*)&q[(size_t)(b * T_ + qbase + row) * H_ + head * HD_ + h8];
    }
    __syncthreads();

    short8 qf[2];
    qf[0] = *(short8*)&Qs[w * 16 + lr][lk8];
    qf[1] = *(short8*)&Qs[w * 16 + lr][32 + lk8];

    f32x4 o[4] = {};
    float m[4] = {-1e30f, -1e30f, -1e30f, -1e30f};
    float lsum[4] = {0.f, 0.f, 0.f, 0.f};

    for (int kt = 0; kt <= qt; ++kt) {
        int kb = kt * 64;
        f32x4 s[4] = {};
#pragma unroll
        for (int ks = 0; ks < 2; ++ks) {
#pragma unroll
            for (int f = 0; f < 4; ++f) {
                short8 kf = *(const short8*)&k[(size_t)(b * T_ + kb + f * 16 + lr) * H_ +
                                               head * HD_ + ks * 32 + lk8];
                s[f] = __builtin_amdgcn_mfma_f32_16x16x32_bf16(qf[ks], kf, s[f], 0, 0, 0);
            }
        }
        if (kt == qt) {
#pragma unroll
            for (int f = 0; f < 4; ++f) {
                int key = kb + f * 16 + lr;
#pragma unroll
                for (int j = 0; j < 4; ++j) {
                    int qrow = qbase + w * 16 + lg4 + j;
                    if (key > qrow) s[f][j] = -1e30f;
                }
            }
        }
#pragma unroll
        for (int j = 0; j < 4; ++j) {
            float mx = fmaxf(fmaxf(s[0][j], s[1][j]), fmaxf(s[2][j], s[3][j]));
#pragma unroll
            for (int off = 1; off < 16; off <<= 1) mx = fmaxf(mx, __shfl_xor(mx, off, 64));
            float mnew = fmaxf(m[j], mx);
            float sc = __expf(m[j] - mnew);
            m[j] = mnew;
            float rs = 0.f;
#pragma unroll
            for (int f = 0; f < 4; ++f) {
                float p = __expf(s[f][j] - mnew);
                s[f][j] = p;
                rs += p;
            }
#pragma unroll
            for (int off = 1; off < 16; off <<= 1) rs += __shfl_xor(rs, off, 64);
            lsum[j] = lsum[j] * sc + rs;
#pragma unroll
            for (int f = 0; f < 4; ++f) o[f][j] *= sc;
#pragma unroll
            for (int f = 0; f < 4; ++f) Ps[w][lg4 + j][f * 16 + lr] = f2bf(s[f][j]);
        }
#pragma unroll
        for (int ks2 = 0; ks2 < 2; ++ks2) {
            short8 pf = *(short8*)&Ps[w][lr][ks2 * 32 + lk8];
#pragma unroll
            for (int f = 0; f < 4; ++f) {
                short8 vf = *(const short8*)&vT[((size_t)(b * HEADS_ + head) * HD_ + f * 16 + lr) * T_ +
                                                kb + ks2 * 32 + lk8];
                o[f] = __builtin_amdgcn_mfma_f32_16x16x32_bf16(pf, vf, o[f], 0, 0, 0);
            }
        }
    }
#pragma unroll
    for (int f = 0; f < 4; ++f)
#pragma unroll
        for (int j = 0; j < 4; ++j) {
            float val = o[f][j] / lsum[j];
            out[(size_t)(b * T_ + qbase + w * 16 + lg4 + j) * H_ + head * HD_ + f * 16 + lr] =
                f2bf(val);
        }
}

// ---------------- launch ----------------
extern "C" void kernel_launch(void* const* d_in, const int* in_sizes, int n_in,
                              void* d_out, int out_size, void* d_ws, size_t ws_size,
                              hipStream_t stream) {
    const float* prefix = (const float*)d_in[0];
    const int* ids = (const int*)d_in[1];
    const float* emb = (const float*)d_in[2];
    const float* Wq = (const float*)d_in[3];
    const float* Wk = (const float*)d_in[4];
    const float* Wv = (const float*)d_in[5];
    const float* Wo = (const float*)d_in[6];
    const float* g1 = (const float*)d_in[7];
    const float* b1 = (const float*)d_in[8];
    const float* g2 = (const float*)d_in[9];
    const float* b2 = (const float*)d_in[10];
    const float* W1 = (const float*)d_in[11];
    const float* bm1 = (const float*)d_in[12];
    const float* W2 = (const float*)d_in[13];
    const float* bm2 = (const float*)d_in[14];
    const float* gf = (const float*)d_in[15];
    const float* bf = (const float*)d_in[16];
    const float* Whead = (const float*)d_in[17];
    float* out = (float*)d_out;

    char* wsp = (char*)d_ws;
    float* x = (float*)wsp;   wsp += (size_t)BT_ * H_ * 4;
    short* h = (short*)wsp;   wsp += (size_t)BT_ * H_ * 2;
    short* qb = (short*)wsp;  wsp += (size_t)BT_ * H_ * 2;
    short* kb = (short*)wsp;  wsp += (size_t)BT_ * H_ * 2;
    short* vT = (short*)wsp;  wsp += (size_t)BT_ * H_ * 2;
    short* ao = (short*)wsp;  wsp += (size_t)BT_ * H_ * 2;
    short* mid = (short*)wsp; wsp += (size_t)BT_ * F_ * 2;
    short* WqkvT = (short*)wsp; wsp += (size_t)NL_ * 3 * H_ * H_ * 2;
    short* WoT = (short*)wsp;   wsp += (size_t)NL_ * H_ * H_ * 2;
    short* W1T = (short*)wsp;   wsp += (size_t)NL_ * H_ * F_ * 2;
    short* W2T = (short*)wsp;   wsp += (size_t)NL_ * F_ * H_ * 2;
    short* WhT = (short*)wsp;   wsp += (size_t)H_ * V_ * 2;

    dim3 blk(256);
    k_cvt_all<<<dim3(56576), blk, 0, stream>>>(Wq, Wk, Wv, Wo, W1, W2, Whead,
                                               WqkvT, WoT, W1T, W2T, WhT);
    k_embed_ln<<<BT_, blk, 0, stream>>>(prefix, ids, emb, g1, b1, x, h);
    for (int l = 0; l < NL_; ++l) {
        size_t o1 = (size_t)l * H_ * H_;
        size_t oq = (size_t)l * 3 * H_ * H_;
        size_t o2 = (size_t)l * H_ * F_;
        k_gemm<3, false, false, false><<<dim3(576), blk, 0, stream>>>(
            h, WqkvT + oq, nullptr, nullptr, qb, kb, vT, BT_, 3 * H_, H_, 1.f);
        k_attn<<<dim3(T_ / 64, HEADS_, B_), blk, 0, stream>>>(qb, kb, vT, ao);
        k_gemm<0, false, false, true><<<dim3(192), blk, 0, stream>>>(
            ao, WoT + o1, nullptr, x, x, nullptr, nullptr, BT_, H_, H_, 1.f);
        k_ln<<<BT_, blk, 0, stream>>>(x, g2 + l * H_, b2 + l * H_, h);
        k_gemm<1, true, true, false><<<dim3(768), blk, 0, stream>>>(
            h, W1T + o2, bm1 + (size_t)l * F_, nullptr, mid, nullptr, nullptr, BT_, F_, H_, 1.f);
        k_gemm<0, true, false, true><<<dim3(192), blk, 0, stream>>>(
            mid, W2T + o2, bm2 + (size_t)l * H_, x, x, nullptr, nullptr, BT_, H_, F_, 1.f);
        const float* gn = (l + 1 < NL_) ? g1 + (l + 1) * H_ : gf;
        const float* bn = (l + 1 < NL_) ? b1 + (l + 1) * H_ : bf;
        k_ln<<<BT_, blk, 0, stream>>>(x, gn, bn, h);
    }
    k_gemm8<<<dim3((BT_ / 256) * (V_ / 256)), dim3(512), 0, stream>>>(
        h, WhT, out, BT_, V_, H_);
}

// Round 6
// 1048.294 us; speedup vs baseline: 2.5891x; 1.0179x over previous
//
#include <hip/hip_runtime.h>
#include <stdint.h>

#define B_ 2
#define P_ 256
#define TL_ 1280
#define T_ 1536
#define H_ 1024
#define HEADS_ 16
#define HD_ 64
#define NL_ 2
#define V_ 32000
#define F_ 4096
#define BT_ (B_ * T_)

typedef __attribute__((ext_vector_type(4))) float f32x4;
typedef __attribute__((ext_vector_type(8))) short short8;
typedef __attribute__((ext_vector_type(4))) short short4v;

typedef __attribute__((address_space(3))) uint32_t lds_u32_t;
typedef const __attribute__((address_space(1))) uint32_t glb_u32_t;

__device__ inline void gload_lds16(const void* g, void* l) {
    __builtin_amdgcn_global_load_lds((glb_u32_t*)g, (lds_u32_t*)l, 16, 0, 0);
}

__device__ inline short f2bf(float f) {
    union { float f; unsigned u; } v; v.f = f;
    unsigned r = v.u + 0x7FFF + ((v.u >> 16) & 1);
    return (short)(r >> 16);
}

#define BAR() asm volatile("s_barrier" ::: "memory")
#define WAIT_VM0() asm volatile("s_waitcnt vmcnt(0)" ::: "memory")
#define WAIT_VM4() asm volatile("s_waitcnt vmcnt(4)" ::: "memory")

// ---------------- fused weight transpose-convert: f32 [K,N] -> bf16 [N,K] ----
__global__ __launch_bounds__(256) void k_cvt_all(
    const float* __restrict__ Wq, const float* __restrict__ Wk,
    const float* __restrict__ Wv, const float* __restrict__ Wo,
    const float* __restrict__ W1, const float* __restrict__ W2,
    const float* __restrict__ Wh,
    short* __restrict__ WqkvT, short* __restrict__ WoT,
    short* __restrict__ W1T, short* __restrict__ W2T, short* __restrict__ WhT) {
    int id = blockIdx.x;
    const float* src;
    short* dst;
    int K, N;
    float scale = 1.f;
    if (id < 6144) {                       // qkv: 2 layers x 3 mats x 1024 tiles
        int mat = id >> 10;
        int tile = id & 1023;
        int l = mat / 3, which = mat - l * 3;
        src = (which == 0 ? Wq : which == 1 ? Wk : Wv) + (size_t)l * H_ * H_;
        dst = WqkvT + (size_t)(l * 3 + which) * H_ * H_;
        K = H_; N = H_;
        if (which == 0) scale = 0.125f;
        id = tile;
    } else if (id < 8192) {                // wo
        int rel = id - 6144;
        int l = rel >> 10;
        src = Wo + (size_t)l * H_ * H_;
        dst = WoT + (size_t)l * H_ * H_;
        K = H_; N = H_;
        id = rel & 1023;
    } else if (id < 16384) {               // w1: K=H, N=F
        int rel = id - 8192;
        int l = rel >> 12;
        src = W1 + (size_t)l * H_ * F_;
        dst = W1T + (size_t)l * H_ * F_;
        K = H_; N = F_;
        id = rel & 4095;
    } else if (id < 24576) {               // w2: K=F, N=H
        int rel = id - 16384;
        int l = rel >> 12;
        src = W2 + (size_t)l * F_ * H_;
        dst = W2T + (size_t)l * F_ * H_;
        K = F_; N = H_;
        id = rel & 4095;
    } else {                               // head: K=H, N=V
        id -= 24576;
        src = Wh; dst = WhT;
        K = H_; N = V_;
    }
    int ntn = N >> 5;
    int nb = (id % ntn) * 32, kb = (id / ntn) * 32;

    __shared__ float ts[32][36];
    int tid = threadIdx.x;
    int r = tid >> 3, c4 = (tid & 7) * 4;
    f32x4 v = *(const f32x4*)&src[(size_t)(kb + r) * N + nb + c4];
    *(f32x4*)&ts[r][c4] = v;
    __syncthreads();
    int wn = tid >> 3, wk4 = (tid & 7) * 4;
    short o[4];
#pragma unroll
    for (int j = 0; j < 4; ++j) o[j] = f2bf(ts[wk4 + j][wn] * scale);
    *(short4v*)&dst[(size_t)(nb + wn) * K + kb + wk4] = *(short4v*)o;
}

// ---------------- embed + concat + first layernorm ---------------------------
__global__ __launch_bounds__(256) void k_embed_ln(const float* __restrict__ prefix,
                                                  const int* __restrict__ ids,
                                                  const float* __restrict__ emb,
                                                  const float* __restrict__ g,
                                                  const float* __restrict__ b,
                                                  float* __restrict__ x,
                                                  short* __restrict__ h) {
    int r = blockIdx.x;
    int bb = r / T_, t = r % T_;
    const float* src = (t < P_) ? (prefix + (size_t)(bb * P_ + t) * H_)
                                : (emb + (size_t)ids[bb * TL_ + (t - P_)] * H_);
    int tid = threadIdx.x;
    f32x4 v = *(const f32x4*)&src[tid * 4];
    *(f32x4*)&x[(size_t)r * H_ + tid * 4] = v;
    float s = v[0] + v[1] + v[2] + v[3];
    float sq = v[0] * v[0] + v[1] * v[1] + v[2] * v[2] + v[3] * v[3];
#pragma unroll
    for (int off = 32; off; off >>= 1) {
        s += __shfl_down(s, off, 64);
        sq += __shfl_down(sq, off, 64);
    }
    __shared__ float red[10];
    int wid = tid >> 6;
    if ((tid & 63) == 0) { red[wid] = s; red[4 + wid] = sq; }
    __syncthreads();
    if (tid == 0) {
        float S = red[0] + red[1] + red[2] + red[3];
        float SQ = red[4] + red[5] + red[6] + red[7];
        float mu = S * (1.0f / H_);
        float var = SQ * (1.0f / H_) - mu * mu;
        red[8] = mu;
        red[9] = rsqrtf(var + 1e-5f);
    }
    __syncthreads();
    float mu = red[8], rstd = red[9];
    short o[4];
#pragma unroll
    for (int j = 0; j < 4; ++j)
        o[j] = f2bf((v[j] - mu) * rstd * g[tid * 4 + j] + b[tid * 4 + j]);
    *(short4v*)&h[(size_t)r * H_ + tid * 4] = *(short4v*)o;
}

// ---------------- layernorm -> bf16 ----------------
__global__ __launch_bounds__(256) void k_ln(const float* __restrict__ x,
                                            const float* __restrict__ g,
                                            const float* __restrict__ b,
                                            short* __restrict__ out) {
    int r = blockIdx.x;
    const float* xr = x + (size_t)r * H_;
    int tid = threadIdx.x;
    f32x4 v = *(const f32x4*)&xr[tid * 4];
    float s = v[0] + v[1] + v[2] + v[3];
    float sq = v[0] * v[0] + v[1] * v[1] + v[2] * v[2] + v[3] * v[3];
#pragma unroll
    for (int off = 32; off; off >>= 1) {
        s += __shfl_down(s, off, 64);
        sq += __shfl_down(sq, off, 64);
    }
    __shared__ float red[10];
    int wid = tid >> 6;
    if ((tid & 63) == 0) { red[wid] = s; red[4 + wid] = sq; }
    __syncthreads();
    if (tid == 0) {
        float S = red[0] + red[1] + red[2] + red[3];
        float SQ = red[4] + red[5] + red[6] + red[7];
        float mu = S * (1.0f / H_);
        float var = SQ * (1.0f / H_) - mu * mu;
        red[8] = mu;
        red[9] = rsqrtf(var + 1e-5f);
    }
    __syncthreads();
    float mu = red[8], rstd = red[9];
    short o[4];
#pragma unroll
    for (int j = 0; j < 4; ++j)
        o[j] = f2bf((v[j] - mu) * rstd * g[tid * 4 + j] + b[tid * 4 + j]);
    *(short4v*)&out[(size_t)r * H_ + tid * 4] = *(short4v*)o;
}

// ---------------- 128x128 GEMM, BK=32, TRIPLE-buffered, counted vmcnt --------
// C = A(bf16[M,K]) * Bt(bf16[N,K])^T.
// Pipeline: iter t stages tile t+2 into buf[(t+2)%3], reads buf[t%3], then
// vmcnt(4) (stage t+1 landed, t+2 in flight; in-order retire) + one barrier.
// Never drains vmcnt to 0 in the main loop (T4) — critical for the grid-192
// dispatches (Wo/W2) that run 1 block/CU with no inter-block TLP.
// STORE: 0 = f32 row-major (+resid), 1 = bf16 row-major,
//        3 = fused QKV split (q bf16 / k bf16 / vT scatter)
template <int STORE, bool HAS_BIAS, bool SILU, bool RES>
__global__ __launch_bounds__(256) void k_gemm(const short* __restrict__ A,
                                              const short* __restrict__ Bt,
                                              const float* __restrict__ bias,
                                              const float* __restrict__ resid,
                                              void* __restrict__ outp,
                                              void* __restrict__ outp2,
                                              void* __restrict__ outp3,
                                              int M, int N, int K, float alpha) {
    __shared__ short As[3][128 * 32];   // 8 KiB per buf, 48 KiB total both
    __shared__ short Bs[3][128 * 32];
    int tid = threadIdx.x;
    int lane = tid & 63, w = tid >> 6;
    int wr = w >> 1, wc = w & 1;
    int nwg = gridDim.x;                 // nwg % 8 == 0 for all our grids
    int mblocks = M >> 7;
    int cpx = nwg >> 3;
    int logical = (blockIdx.x & 7) * cpx + (blockIdx.x >> 3);
    int rp = logical % mblocks, cp = logical / mblocks;
    int mbase = rp * 128, nbase = cp * 128;
    int lr = lane & 15, hi = lane >> 4;
    int lg = hi * 4;

    f32x4 acc[4][4] = {};

    // staging: thread covers LDS 16B slots tid and tid+256 (rows r0, r0+64)
    int r0 = tid >> 2;
    int gcol = ((tid & 3) ^ (r0 & 3)) * 8;          // inverse-swizzled source col
    const short* Ab = A + (size_t)mbase * K;
    const short* Bb = Bt + (size_t)nbase * K;

    // fragment read byte offsets: row*64 + swizzled k-slot
    int koff = ((hi ^ (lr & 3)) << 4);
    int arow[4], brow[4];
#pragma unroll
    for (int m = 0; m < 4; ++m) arow[m] = (wr * 64 + m * 16 + lr) * 64;
#pragma unroll
    for (int n = 0; n < 4; ++n) brow[n] = (wc * 64 + n * 16 + lr) * 64;

    auto stage = [&](int t, int buf) {
        const short* ga = Ab + (size_t)r0 * K + t * 32 + gcol;
        const short* gb = Bb + (size_t)r0 * K + t * 32 + gcol;
        char* la = (char*)&As[buf][0];
        char* lb = (char*)&Bs[buf][0];
        gload_lds16(ga, la + tid * 16);
        gload_lds16(ga + (size_t)64 * K, la + tid * 16 + 4096);
        gload_lds16(gb, lb + tid * 16);
        gload_lds16(gb + (size_t)64 * K, lb + tid * 16 + 4096);
    };

    int NT = K >> 5;                      // >= 32 for all our shapes
    stage(0, 0);
    stage(1, 1);
    WAIT_VM4();                           // tile 0 landed; tile 1 in flight
    BAR();

    int cur = 0;
    for (int t = 0; t < NT; ++t) {
        bool iss = (t + 2 < NT);
        int nb2 = cur + 2; if (nb2 >= 3) nb2 -= 3;
        if (iss) stage(t + 2, nb2);
        const char* a = (const char*)&As[cur][0];
        const char* b = (const char*)&Bs[cur][0];
        short8 af[4], bfr[4];
#pragma unroll
        for (int mi = 0; mi < 4; ++mi) af[mi] = *(const short8*)(a + arow[mi] + koff);
#pragma unroll
        for (int ni = 0; ni < 4; ++ni) bfr[ni] = *(const short8*)(b + brow[ni] + koff);
        __builtin_amdgcn_s_setprio(1);
#pragma unroll
        for (int mi = 0; mi < 4; ++mi)
#pragma unroll
            for (int ni = 0; ni < 4; ++ni)
                acc[mi][ni] = __builtin_amdgcn_mfma_f32_16x16x32_bf16(af[mi], bfr[ni], acc[mi][ni], 0, 0, 0);
        __builtin_amdgcn_s_setprio(0);
        if (t + 1 < NT) {
            if (iss) WAIT_VM4(); else WAIT_VM0();   // next tile guaranteed landed
            BAR();
        }
        cur += 1; if (cur == 3) cur = 0;
    }

#pragma unroll
    for (int ni = 0; ni < 4; ++ni) {
        int col = nbase + wc * 64 + ni * 16 + lr;
        float bv = HAS_BIAS ? bias[col] : 0.f;
#pragma unroll
        for (int mi = 0; mi < 4; ++mi) {
#pragma unroll
            for (int j = 0; j < 4; ++j) {
                int row = mbase + wr * 64 + mi * 16 + lg + j;
                float vv = acc[mi][ni][j] * alpha + bv;
                if (SILU) vv = vv / (1.f + __expf(-vv));
                if (RES) vv += resid[(size_t)row * N + col];
                if (STORE == 0) {
                    ((float*)outp)[(size_t)row * N + col] = vv;
                } else if (STORE == 1) {
                    ((short*)outp)[(size_t)row * N + col] = f2bf(vv);
                } else {  // STORE == 3: fused QKV
                    int seg = col >> 10;
                    int c = col & 1023;
                    if (seg == 0) {
                        ((short*)outp)[(size_t)row * H_ + c] = f2bf(vv);
                    } else if (seg == 1) {
                        ((short*)outp2)[(size_t)row * H_ + c] = f2bf(vv);
                    } else {
                        int bb = row / T_, t2 = row % T_;
                        ((short*)outp3)[((size_t)(bb * HEADS_ + (c >> 6)) * HD_ + (c & 63)) * T_ + t2] = f2bf(vv);
                    }
                }
            }
        }
    }
}

// ---------------- 8-phase 256x256 GEMM (T2+T3+T4+T5), f32 output -------------
// Verified 257 us / 783 TF. 1 block/CU by design; intra-block phase overlap.
// DO NOT cap registers below 256/wave (round-3 post-mortem: spills, 7.5x slow).
__global__ __launch_bounds__(512, 2) void k_gemm8(const short* __restrict__ A,
                                                  const short* __restrict__ Bt,
                                                  float* __restrict__ C,
                                                  int M, int N, int K) {
    __shared__ short As[2 * 256 * 64];   // 64 KiB
    __shared__ short Bs[2 * 256 * 64];   // 64 KiB
    int tid = threadIdx.x;
    int lane = tid & 63, w = tid >> 6;
    int wr = w >> 2, wc = w & 3;         // 2 x 4 waves; wave owns 128x64 of C
    int lr = lane & 15, hi = lane >> 4;

    // bijective XCD swizzle (m204 form; works for any nwg)
    int mtiles = M >> 8;
    int nwg = gridDim.x;
    int q = nwg >> 3, r = nwg & 7;
    int xcd = blockIdx.x & 7, lid = blockIdx.x >> 3;
    int wgid = (xcd < r ? xcd * (q + 1) : r * (q + 1) + (xcd - r) * q) + lid;
    int rp = wgid % mtiles, cp = wgid / mtiles;   // M-major: B-panel reuse in L2

    const short* Ab = A + (size_t)rp * 256 * K;
    const short* Bb = Bt + (size_t)cp * 256 * K;

    int r0 = tid >> 3;                              // row within half (load 0)
    int gcol = ((tid & 7) ^ (r0 & 7)) * 8;          // bf16 col within 64-k tile

    int koff0 = (hi * 16) ^ ((lr & 7) << 4);
    int koff1 = (64 + hi * 16) ^ ((lr & 7) << 4);
    int arow[8], brow[4];
#pragma unroll
    for (int m = 0; m < 8; ++m) arow[m] = (wr * 128 + m * 16 + lr) * 128;
#pragma unroll
    for (int n = 0; n < 4; ++n) brow[n] = (wc * 64 + n * 16 + lr) * 128;

    f32x4 acc[8][4] = {};
    short8 aF[4][2], bF[4][2];
    const char* Ac = (const char*)As;
    const char* Bc = (const char*)Bs;

    auto stage = [&](const short* Gb, char* Lb, int tau, int hf) {
        const short* g0 = Gb + (size_t)(hf * 128 + r0) * K + tau * 64 + gcol;
        char* l = Lb + (tau & 1) * 32768 + hf * 16384;
        gload_lds16(g0, l + tid * 16);
        gload_lds16(g0 + (size_t)64 * K, l + (tid + 512) * 16);
    };
    auto lda4 = [&](const char* base, int roff) {
#pragma unroll
        for (int m = 0; m < 4; ++m) {
            aF[m][0] = *(const short8*)(base + arow[roff + m] + koff0);
            aF[m][1] = *(const short8*)(base + arow[roff + m] + koff1);
        }
    };
    auto ldb2 = [&](const char* base, int noff) {
#pragma unroll
        for (int n = 0; n < 2; ++n) {
            bF[noff + n][0] = *(const short8*)(base + brow[noff + n] + koff0);
            bF[noff + n][1] = *(const short8*)(base + brow[noff + n] + koff1);
        }
    };

#define MFMA_QUAD(MOFF, NOFF)                                                          \
    __builtin_amdgcn_s_setprio(1);                                                     \
    _Pragma("unroll") for (int m = 0; m < 4; ++m) {                                    \
        _Pragma("unroll") for (int n = 0; n < 2; ++n) {                                \
            acc[MOFF + m][NOFF + n] = __builtin_amdgcn_mfma_f32_16x16x32_bf16(         \
                aF[m][0], bF[NOFF + n][0], acc[MOFF + m][NOFF + n], 0, 0, 0);          \
            acc[MOFF + m][NOFF + n] = __builtin_amdgcn_mfma_f32_16x16x32_bf16(         \
                aF[m][1], bF[NOFF + n][1], acc[MOFF + m][NOFF + n], 0, 0, 0);          \
        }                                                                              \
    }                                                                                  \
    __builtin_amdgcn_s_setprio(0);

    int NK = K >> 6;
    stage(Ab, (char*)As, 0, 0); stage(Ab, (char*)As, 0, 1);
    stage(Bb, (char*)Bs, 0, 0); stage(Bb, (char*)Bs, 0, 1);
    stage(Ab, (char*)As, 1, 0); stage(Ab, (char*)As, 1, 1);
    stage(Bb, (char*)Bs, 1, 0); stage(Bb, (char*)Bs, 1, 1);
    asm volatile("s_waitcnt vmcnt(0)" ::: "memory");
    BAR();

    int niters = NK >> 1;
    for (int it = 0; it < niters; ++it) {
        bool st = it < niters - 1;
        int u2 = 2 * it + 2, v2 = 2 * it + 3;
        const char* a0 = Ac;            const char* b0 = Bc;
        const char* a1 = Ac + 32768;    const char* b1 = Bc + 32768;

        // ===== tile u (buf0), phases 1-4 =====
        lda4(a0, 0); ldb2(b0, 0);
        BAR();
        MFMA_QUAD(0, 0);
        BAR();
        ldb2(b0, 2);
        BAR();
        MFMA_QUAD(0, 2);
        BAR();
        lda4(a0, 4);
        if (st) stage(Bb, (char*)Bs, u2, 0);
        BAR();
        MFMA_QUAD(4, 0);
        BAR();
        if (st) stage(Bb, (char*)Bs, u2, 1);
        BAR();
        MFMA_QUAD(4, 2);
        asm volatile("s_waitcnt vmcnt(4)" ::: "memory");
        BAR();

        // ===== tile v (buf1), phases 5-8 =====
        lda4(a1, 0); ldb2(b1, 0);
        if (st) stage(Ab, (char*)As, u2, 0);
        BAR();
        MFMA_QUAD(0, 0);
        BAR();
        ldb2(b1, 2);
        if (st) stage(Ab, (char*)As, u2, 1);
        BAR();
        MFMA_QUAD(0, 2);
        BAR();
        lda4(a1, 4);
        if (st) stage(Bb, (char*)Bs, v2, 0);
        BAR();
        MFMA_QUAD(4, 0);
        BAR();
        if (st) { stage(Bb, (char*)Bs, v2, 1); stage(Ab, (char*)As, v2, 0); stage(Ab, (char*)As, v2, 1); }
        BAR();
        MFMA_QUAD(4, 2);
        asm volatile("s_waitcnt vmcnt(8)" ::: "memory");
        BAR();
    }

    int crow = rp * 256 + wr * 128 + hi * 4;
    int ccol = cp * 256 + wc * 64 + lr;
#pragma unroll
    for (int m = 0; m < 8; ++m)
#pragma unroll
        for (int n = 0; n < 4; ++n) {
#pragma unroll
            for (int j = 0; j < 4; ++j)
                C[(size_t)(crow + m * 16 + j) * N + ccol + n * 16] = acc[m][n][j];
        }
#undef MFMA_QUAD
}

// ---------------- flash attention ----------------
__global__ __launch_bounds__(256) void k_attn(const short* __restrict__ q,
                                              const short* __restrict__ k,
                                              const short* __restrict__ vT,
                                              short* __restrict__ out) {
    int qt = blockIdx.x, head = blockIdx.y, b = blockIdx.z;
    int qbase = qt * 64;
    __shared__ short Qs[64][72];
    __shared__ short Ps[4][16][72];
    int tid = threadIdx.x, lane = tid & 63, w = tid >> 6;
    int lr = lane & 15, lg4 = (lane >> 4) * 4, lk8 = (lane >> 4) * 8;

#pragma unroll
    for (int c = 0; c < 2; ++c) {
        int chunk = tid + 256 * c;
        int row = chunk >> 3, h8 = (chunk & 7) * 8;
        *(short8*)&Qs[row][h8] =
            *(const short8*)&q[(size_t)(b * T_ + qbase + row) * H_ + head * HD_ + h8];
    }
    __syncthreads();

    short8 qf[2];
    qf[0] = *(short8*)&Qs[w * 16 + lr][lk8];
    qf[1] = *(short8*)&Qs[w * 16 + lr][32 + lk8];

    f32x4 o[4] = {};
    float m[4] = {-1e30f, -1e30f, -1e30f, -1e30f};
    float lsum[4] = {0.f, 0.f, 0.f, 0.f};

    for (int kt = 0; kt <= qt; ++kt) {
        int kb = kt * 64;
        f32x4 s[4] = {};
#pragma unroll
        for (int ks = 0; ks < 2; ++ks) {
#pragma unroll
            for (int f = 0; f < 4; ++f) {
                short8 kf = *(const short8*)&k[(size_t)(b * T_ + kb + f * 16 + lr) * H_ +
                                               head * HD_ + ks * 32 + lk8];
                s[f] = __builtin_amdgcn_mfma_f32_16x16x32_bf16(qf[ks], kf, s[f], 0, 0, 0);
            }
        }
        if (kt == qt) {
#pragma unroll
            for (int f = 0; f < 4; ++f) {
                int key = kb + f * 16 + lr;
#pragma unroll
                for (int j = 0; j < 4; ++j) {
                    int qrow = qbase + w * 16 + lg4 + j;
                    if (key > qrow) s[f][j] = -1e30f;
                }
            }
        }
#pragma unroll
        for (int j = 0; j < 4; ++j) {
            float mx = fmaxf(fmaxf(s[0][j], s[1][j]), fmaxf(s[2][j], s[3][j]));
#pragma unroll
            for (int off = 1; off < 16; off <<= 1) mx = fmaxf(mx, __shfl_xor(mx, off, 64));
            float mnew = fmaxf(m[j], mx);
            float sc = __expf(m[j] - mnew);
            m[j] = mnew;
            float rs = 0.f;
#pragma unroll
            for (int f = 0; f < 4; ++f) {
                float p = __expf(s[f][j] - mnew);
                s[f][j] = p;
                rs += p;
            }
#pragma unroll
            for (int off = 1; off < 16; off <<= 1) rs += __shfl_xor(rs, off, 64);
            lsum[j] = lsum[j] * sc + rs;
#pragma unroll
            for (int f = 0; f < 4; ++f) o[f][j] *= sc;
#pragma unroll
            for (int f = 0; f < 4; ++f) Ps[w][lg4 + j][f * 16 + lr] = f2bf(s[f][j]);
        }
#pragma unroll
        for (int ks2 = 0; ks2 < 2; ++ks2) {
            short8 pf = *(short8*)&Ps[w][lr][ks2 * 32 + lk8];
            __builtin_amdgcn_s_setprio(1);
#pragma unroll
            for (int f = 0; f < 4; ++f) {
                short8 vf = *(const short8*)&vT[((size_t)(b * HEADS_ + head) * HD_ + f * 16 + lr) * T_ +
                                                kb + ks2 * 32 + lk8];
                o[f] = __builtin_amdgcn_mfma_f32_16x16x32_bf16(pf, vf, o[f], 0, 0, 0);
            }
            __builtin_amdgcn_s_setprio(0);
        }
    }
#pragma unroll
    for (int f = 0; f < 4; ++f)
#pragma unroll
        for (int j = 0; j < 4; ++j) {
            float val = o[f][j] / lsum[j];
            out[(size_t)(b * T_ + qbase + w * 16 + lg4 + j) * H_ + head * HD_ + f * 16 + lr] =
                f2bf(val);
        }
}

// ---------------- launch ----------------
extern "C" void kernel_launch(void* const* d_in, const int* in_sizes, int n_in,
                              void* d_out, int out_size, void* d_ws, size_t ws_size,
                              hipStream_t stream) {
    const float* prefix = (const float*)d_in[0];
    const int* ids = (const int*)d_in[1];
    const float* emb = (const float*)d_in[2];
    const float* Wq = (const float*)d_in[3];
    const float* Wk = (const float*)d_in[4];
    const float* Wv = (const float*)d_in[5];
    const float* Wo = (const float*)d_in[6];
    const float* g1 = (const float*)d_in[7];
    const float* b1 = (const float*)d_in[8];
    const float* g2 = (const float*)d_in[9];
    const float* b2 = (const float*)d_in[10];
    const float* W1 = (const float*)d_in[11];
    const float* bm1 = (const float*)d_in[12];
    const float* W2 = (const float*)d_in[13];
    const float* bm2 = (const float*)d_in[14];
    const float* gf = (const float*)d_in[15];
    const float* bf = (const float*)d_in[16];
    const float* Whead = (const float*)d_in[17];
    float* out = (float*)d_out;

    char* wsp = (char*)d_ws;
    float* x = (float*)wsp;   wsp += (size_t)BT_ * H_ * 4;
    short* h = (short*)wsp;   wsp += (size_t)BT_ * H_ * 2;
    short* qb = (short*)wsp;  wsp += (size_t)BT_ * H_ * 2;
    short* kb = (short*)wsp;  wsp += (size_t)BT_ * H_ * 2;
    short* vT = (short*)wsp;  wsp += (size_t)BT_ * H_ * 2;
    short* ao = (short*)wsp;  wsp += (size_t)BT_ * H_ * 2;
    short* mid = (short*)wsp; wsp += (size_t)BT_ * F_ * 2;
    short* WqkvT = (short*)wsp; wsp += (size_t)NL_ * 3 * H_ * H_ * 2;
    short* WoT = (short*)wsp;   wsp += (size_t)NL_ * H_ * H_ * 2;
    short* W1T = (short*)wsp;   wsp += (size_t)NL_ * H_ * F_ * 2;
    short* W2T = (short*)wsp;   wsp += (size_t)NL_ * F_ * H_ * 2;
    short* WhT = (short*)wsp;   wsp += (size_t)H_ * V_ * 2;

    dim3 blk(256);
    k_cvt_all<<<dim3(56576), blk, 0, stream>>>(Wq, Wk, Wv, Wo, W1, W2, Whead,
                                               WqkvT, WoT, W1T, W2T, WhT);
    k_embed_ln<<<BT_, blk, 0, stream>>>(prefix, ids, emb, g1, b1, x, h);
    for (int l = 0; l < NL_; ++l) {
        size_t o1 = (size_t)l * H_ * H_;
        size_t oq = (size_t)l * 3 * H_ * H_;
        size_t o2 = (size_t)l * H_ * F_;
        k_gemm<3, false, false, false><<<dim3(576), blk, 0, stream>>>(
            h, WqkvT + oq, nullptr, nullptr, qb, kb, vT, BT_, 3 * H_, H_, 1.f);
        k_attn<<<dim3(T_ / 64, HEADS_, B_), blk, 0, stream>>>(qb, kb, vT, ao);
        k_gemm<0, false, false, true><<<dim3(192), blk, 0, stream>>>(
            ao, WoT + o1, nullptr, x, x, nullptr, nullptr, BT_, H_, H_, 1.f);
        k_ln<<<BT_, blk, 0, stream>>>(x, g2 + l * H_, b2 + l * H_, h);
        k_gemm<1, true, true, false><<<dim3(768), blk, 0, stream>>>(
            h, W1T + o2, bm1 + (size_t)l * F_, nullptr, mid, nullptr, nullptr, BT_, F_, H_, 1.f);
        k_gemm<0, true, false, true><<<dim3(192), blk, 0, stream>>>(
            mid, W2T + o2, bm2 + (size_t)l * H_, x, x, nullptr, nullptr, BT_, H_, F_, 1.f);
        const float* gn = (l + 1 < NL_) ? g1 + (l + 1) * H_ : gf;
        const float* bn = (l + 1 < NL_) ? b1 + (l + 1) * H_ : bf;
        k_ln<<<BT_, blk, 0, stream>>>(x, gn, bn, h);
    }
    k_gemm8<<<dim3((BT_ / 256) * (V_ / 256)), dim3(512), 0, stream>>>(
        h, WhT, out, BT_, V_, H_);
}

// Round 7
// 1016.938 us; speedup vs baseline: 2.6690x; 1.0308x over previous
//
#include <hip/hip_runtime.h>
#include <stdint.h>

#define B_ 2
#define P_ 256
#define TL_ 1280
#define T_ 1536
#define H_ 1024
#define HEADS_ 16
#define HD_ 64
#define NL_ 2
#define V_ 32000
#define F_ 4096
#define BT_ (B_ * T_)

typedef __attribute__((ext_vector_type(4))) float f32x4;
typedef __attribute__((ext_vector_type(8))) short short8;
typedef __attribute__((ext_vector_type(4))) short short4v;

typedef __attribute__((address_space(3))) uint32_t lds_u32_t;
typedef const __attribute__((address_space(1))) uint32_t glb_u32_t;

__device__ inline void gload_lds16(const void* g, void* l) {
    __builtin_amdgcn_global_load_lds((glb_u32_t*)g, (lds_u32_t*)l, 16, 0, 0);
}

__device__ inline short f2bf(float f) {
    union { float f; unsigned u; } v; v.f = f;
    unsigned r = v.u + 0x7FFF + ((v.u >> 16) & 1);
    return (short)(r >> 16);
}

#define BAR() asm volatile("s_barrier" ::: "memory")
#define WAIT_VM0() asm volatile("s_waitcnt vmcnt(0)" ::: "memory")
#define WAIT_VM4() asm volatile("s_waitcnt vmcnt(4)" ::: "memory")
#define WAIT_VM8() asm volatile("s_waitcnt vmcnt(8)" ::: "memory")

// ---------------- fused weight transpose-convert: f32 [K,N] -> bf16 [N,K] ----
__global__ __launch_bounds__(256) void k_cvt_all(
    const float* __restrict__ Wq, const float* __restrict__ Wk,
    const float* __restrict__ Wv, const float* __restrict__ Wo,
    const float* __restrict__ W1, const float* __restrict__ W2,
    const float* __restrict__ Wh,
    short* __restrict__ WqkvT, short* __restrict__ WoT,
    short* __restrict__ W1T, short* __restrict__ W2T, short* __restrict__ WhT) {
    int id = blockIdx.x;
    const float* src;
    short* dst;
    int K, N;
    float scale = 1.f;
    if (id < 6144) {                       // qkv: 2 layers x 3 mats x 1024 tiles
        int mat = id >> 10;
        int tile = id & 1023;
        int l = mat / 3, which = mat - l * 3;
        src = (which == 0 ? Wq : which == 1 ? Wk : Wv) + (size_t)l * H_ * H_;
        dst = WqkvT + (size_t)(l * 3 + which) * H_ * H_;
        K = H_; N = H_;
        if (which == 0) scale = 0.125f;
        id = tile;
    } else if (id < 8192) {                // wo
        int rel = id - 6144;
        int l = rel >> 10;
        src = Wo + (size_t)l * H_ * H_;
        dst = WoT + (size_t)l * H_ * H_;
        K = H_; N = H_;
        id = rel & 1023;
    } else if (id < 16384) {               // w1: K=H, N=F
        int rel = id - 8192;
        int l = rel >> 12;
        src = W1 + (size_t)l * H_ * F_;
        dst = W1T + (size_t)l * H_ * F_;
        K = H_; N = F_;
        id = rel & 4095;
    } else if (id < 24576) {               // w2: K=F, N=H
        int rel = id - 16384;
        int l = rel >> 12;
        src = W2 + (size_t)l * F_ * H_;
        dst = W2T + (size_t)l * F_ * H_;
        K = F_; N = H_;
        id = rel & 4095;
    } else {                               // head: K=H, N=V
        id -= 24576;
        src = Wh; dst = WhT;
        K = H_; N = V_;
    }
    int ntn = N >> 5;
    int nb = (id % ntn) * 32, kb = (id / ntn) * 32;

    __shared__ float ts[32][36];
    int tid = threadIdx.x;
    int r = tid >> 3, c4 = (tid & 7) * 4;
    f32x4 v = *(const f32x4*)&src[(size_t)(kb + r) * N + nb + c4];
    *(f32x4*)&ts[r][c4] = v;
    __syncthreads();
    int wn = tid >> 3, wk4 = (tid & 7) * 4;
    short o[4];
#pragma unroll
    for (int j = 0; j < 4; ++j) o[j] = f2bf(ts[wk4 + j][wn] * scale);
    *(short4v*)&dst[(size_t)(nb + wn) * K + kb + wk4] = *(short4v*)o;
}

// ---------------- embed + concat + first layernorm ---------------------------
__global__ __launch_bounds__(256) void k_embed_ln(const float* __restrict__ prefix,
                                                  const int* __restrict__ ids,
                                                  const float* __restrict__ emb,
                                                  const float* __restrict__ g,
                                                  const float* __restrict__ b,
                                                  float* __restrict__ x,
                                                  short* __restrict__ h) {
    int r = blockIdx.x;
    int bb = r / T_, t = r % T_;
    const float* src = (t < P_) ? (prefix + (size_t)(bb * P_ + t) * H_)
                                : (emb + (size_t)ids[bb * TL_ + (t - P_)] * H_);
    int tid = threadIdx.x;
    f32x4 v = *(const f32x4*)&src[tid * 4];
    *(f32x4*)&x[(size_t)r * H_ + tid * 4] = v;
    float s = v[0] + v[1] + v[2] + v[3];
    float sq = v[0] * v[0] + v[1] * v[1] + v[2] * v[2] + v[3] * v[3];
#pragma unroll
    for (int off = 32; off; off >>= 1) {
        s += __shfl_down(s, off, 64);
        sq += __shfl_down(sq, off, 64);
    }
    __shared__ float red[10];
    int wid = tid >> 6;
    if ((tid & 63) == 0) { red[wid] = s; red[4 + wid] = sq; }
    __syncthreads();
    if (tid == 0) {
        float S = red[0] + red[1] + red[2] + red[3];
        float SQ = red[4] + red[5] + red[6] + red[7];
        float mu = S * (1.0f / H_);
        float var = SQ * (1.0f / H_) - mu * mu;
        red[8] = mu;
        red[9] = rsqrtf(var + 1e-5f);
    }
    __syncthreads();
    float mu = red[8], rstd = red[9];
    short o[4];
#pragma unroll
    for (int j = 0; j < 4; ++j)
        o[j] = f2bf((v[j] - mu) * rstd * g[tid * 4 + j] + b[tid * 4 + j]);
    *(short4v*)&h[(size_t)r * H_ + tid * 4] = *(short4v*)o;
}

// ---------------- x += p0 + p1 (split-K combine), then layernorm -> bf16 -----
__global__ __launch_bounds__(256) void k_add_ln(float* __restrict__ x,
                                                const float* __restrict__ p0,
                                                const float* __restrict__ p1,
                                                const float* __restrict__ g,
                                                const float* __restrict__ b,
                                                short* __restrict__ out) {
    int r = blockIdx.x;
    int tid = threadIdx.x;
    size_t base = (size_t)r * H_ + tid * 4;
    f32x4 v = *(f32x4*)&x[base];
    f32x4 a0 = *(const f32x4*)&p0[base];
    f32x4 a1 = *(const f32x4*)&p1[base];
#pragma unroll
    for (int j = 0; j < 4; ++j) v[j] += a0[j] + a1[j];
    *(f32x4*)&x[base] = v;
    float s = v[0] + v[1] + v[2] + v[3];
    float sq = v[0] * v[0] + v[1] * v[1] + v[2] * v[2] + v[3] * v[3];
#pragma unroll
    for (int off = 32; off; off >>= 1) {
        s += __shfl_down(s, off, 64);
        sq += __shfl_down(sq, off, 64);
    }
    __shared__ float red[10];
    int wid = tid >> 6;
    if ((tid & 63) == 0) { red[wid] = s; red[4 + wid] = sq; }
    __syncthreads();
    if (tid == 0) {
        float S = red[0] + red[1] + red[2] + red[3];
        float SQ = red[4] + red[5] + red[6] + red[7];
        float mu = S * (1.0f / H_);
        float var = SQ * (1.0f / H_) - mu * mu;
        red[8] = mu;
        red[9] = rsqrtf(var + 1e-5f);
    }
    __syncthreads();
    float mu = red[8], rstd = red[9];
    short o[4];
#pragma unroll
    for (int j = 0; j < 4; ++j)
        o[j] = f2bf((v[j] - mu) * rstd * g[tid * 4 + j] + b[tid * 4 + j]);
    *(short4v*)&out[base] = *(short4v*)o;
}

// ---------------- 128x128 GEMM, BK=32, QUAD-buffered, prefetch depth 3 -------
// C = A(bf16[M,K]) * Bt(bf16[N,K])^T.
// Iter t: stage tile t+3 into buf[(t+3)&3], read buf[t&3], MFMA, then
// vmcnt(8) (tile t+1 landed ~2 iters after issue ≈ HBM latency covered).
// LDS 64 KiB -> 2 blocks/CU.  Weights are read-once (always HBM miss), so
// prefetch distance must cover ~900 cy — distance-1 (round 5) did not.
// STORE: 0 = f32 row-major raw (split-K slice target), 1 = bf16 (+bias+silu),
//        3 = fused QKV split (q bf16 / k bf16 / vT scatter)
// KSPLIT: grid doubled; ks = logical tile-id half; A/B column-offset ks*K/2,
//         output offset ks*M*N; bias applied only in slice 0.
template <int STORE, bool HAS_BIAS, bool SILU, bool KSPLIT>
__global__ __launch_bounds__(256) void k_gemm(const short* __restrict__ A,
                                              const short* __restrict__ Bt,
                                              const float* __restrict__ bias,
                                              void* __restrict__ outp,
                                              void* __restrict__ outp2,
                                              void* __restrict__ outp3,
                                              int M, int N, int K, float alpha) {
    __shared__ short As[4][128 * 32];   // 8 KiB per buf; 64 KiB total A+B
    __shared__ short Bs[4][128 * 32];
    int tid = threadIdx.x;
    int lane = tid & 63, w = tid >> 6;
    int wr = w >> 1, wc = w & 1;
    int nwg = gridDim.x;                 // nwg % 8 == 0 for all our grids
    int mblocks = M >> 7;
    int cpx = nwg >> 3;
    int logical = (blockIdx.x & 7) * cpx + (blockIdx.x >> 3);
    int ks = 0;
    if (KSPLIT) {
        int half = mblocks * (N >> 7);
        if (logical >= half) { ks = 1; logical -= half; }
    }
    int rp = logical % mblocks, cp = logical / mblocks;
    int mbase = rp * 128, nbase = cp * 128;
    int Kh = KSPLIT ? (K >> 1) : K;
    int lr = lane & 15, hi = lane >> 4;
    int lg = hi * 4;

    f32x4 acc[4][4] = {};

    // staging: thread covers LDS 16B slots tid and tid+256 (rows r0, r0+64)
    int r0 = tid >> 2;
    int gcol = ((tid & 3) ^ (r0 & 3)) * 8;          // inverse-swizzled source col
    const short* Ab = A + (size_t)mbase * K + (size_t)ks * Kh;
    const short* Bb = Bt + (size_t)nbase * K + (size_t)ks * Kh;

    // fragment read byte offsets: row*64 + swizzled k-slot
    int koff = ((hi ^ (lr & 3)) << 4);
    int arow[4], brow[4];
#pragma unroll
    for (int m = 0; m < 4; ++m) arow[m] = (wr * 64 + m * 16 + lr) * 64;
#pragma unroll
    for (int n = 0; n < 4; ++n) brow[n] = (wc * 64 + n * 16 + lr) * 64;

    auto stage = [&](int t, int buf) {
        const short* ga = Ab + (size_t)r0 * K + t * 32 + gcol;
        const short* gb = Bb + (size_t)r0 * K + t * 32 + gcol;
        char* la = (char*)&As[buf][0];
        char* lb = (char*)&Bs[buf][0];
        gload_lds16(ga, la + tid * 16);
        gload_lds16(ga + (size_t)64 * K, la + tid * 16 + 4096);
        gload_lds16(gb, lb + tid * 16);
        gload_lds16(gb + (size_t)64 * K, lb + tid * 16 + 4096);
    };

    int NT = Kh >> 5;                     // >= 16 for all our shapes
    stage(0, 0);
    stage(1, 1);
    stage(2, 2);
    WAIT_VM8();                           // tile 0 landed; 1,2 in flight
    BAR();

    for (int t = 0; t < NT; ++t) {
        bool iss = (t + 3 < NT);
        if (iss) stage(t + 3, (t + 3) & 3);
        const char* a = (const char*)&As[t & 3][0];
        const char* b = (const char*)&Bs[t & 3][0];
        short8 af[4], bfr[4];
#pragma unroll
        for (int mi = 0; mi < 4; ++mi) af[mi] = *(const short8*)(a + arow[mi] + koff);
#pragma unroll
        for (int ni = 0; ni < 4; ++ni) bfr[ni] = *(const short8*)(b + brow[ni] + koff);
        __builtin_amdgcn_s_setprio(1);
#pragma unroll
        for (int mi = 0; mi < 4; ++mi)
#pragma unroll
            for (int ni = 0; ni < 4; ++ni)
                acc[mi][ni] = __builtin_amdgcn_mfma_f32_16x16x32_bf16(af[mi], bfr[ni], acc[mi][ni], 0, 0, 0);
        __builtin_amdgcn_s_setprio(0);
        if (t + 1 < NT) {
            if (iss) WAIT_VM8();                 // t+1 landed (2 newer in flight)
            else if (t + 2 < NT) WAIT_VM4();     // tail: t+1, t+2 in flight
            else WAIT_VM0();                     // tail: only t+1 in flight
            BAR();
        }
    }

#pragma unroll
    for (int ni = 0; ni < 4; ++ni) {
        int col = nbase + wc * 64 + ni * 16 + lr;
        float bv = (HAS_BIAS && ks == 0) ? bias[col] : 0.f;
#pragma unroll
        for (int mi = 0; mi < 4; ++mi) {
#pragma unroll
            for (int j = 0; j < 4; ++j) {
                int row = mbase + wr * 64 + mi * 16 + lg + j;
                float vv = acc[mi][ni][j] * alpha + bv;
                if (SILU) vv = vv / (1.f + __expf(-vv));
                if (STORE == 0) {
                    ((float*)outp)[(size_t)ks * M * N + (size_t)row * N + col] = vv;
                } else if (STORE == 1) {
                    ((short*)outp)[(size_t)row * N + col] = f2bf(vv);
                } else {  // STORE == 3: fused QKV
                    int seg = col >> 10;
                    int c = col & 1023;
                    if (seg == 0) {
                        ((short*)outp)[(size_t)row * H_ + c] = f2bf(vv);
                    } else if (seg == 1) {
                        ((short*)outp2)[(size_t)row * H_ + c] = f2bf(vv);
                    } else {
                        int bb = row / T_, t2 = row % T_;
                        ((short*)outp3)[((size_t)(bb * HEADS_ + (c >> 6)) * HD_ + (c & 63)) * T_ + t2] = f2bf(vv);
                    }
                }
            }
        }
    }
}

// ---------------- 8-phase 256x256 GEMM (T2+T3+T4+T5), f32 output -------------
// Verified 257 us / 783 TF. 1 block/CU by design; intra-block phase overlap.
// DO NOT cap registers below 256/wave (round-3 post-mortem: spills, 7.5x slow).
__global__ __launch_bounds__(512, 2) void k_gemm8(const short* __restrict__ A,
                                                  const short* __restrict__ Bt,
                                                  float* __restrict__ C,
                                                  int M, int N, int K) {
    __shared__ short As[2 * 256 * 64];   // 64 KiB
    __shared__ short Bs[2 * 256 * 64];   // 64 KiB
    int tid = threadIdx.x;
    int lane = tid & 63, w = tid >> 6;
    int wr = w >> 2, wc = w & 3;         // 2 x 4 waves; wave owns 128x64 of C
    int lr = lane & 15, hi = lane >> 4;

    // bijective XCD swizzle (m204 form; works for any nwg)
    int mtiles = M >> 8;
    int nwg = gridDim.x;
    int q = nwg >> 3, r = nwg & 7;
    int xcd = blockIdx.x & 7, lid = blockIdx.x >> 3;
    int wgid = (xcd < r ? xcd * (q + 1) : r * (q + 1) + (xcd - r) * q) + lid;
    int rp = wgid % mtiles, cp = wgid / mtiles;   // M-major: B-panel reuse in L2

    const short* Ab = A + (size_t)rp * 256 * K;
    const short* Bb = Bt + (size_t)cp * 256 * K;

    int r0 = tid >> 3;                              // row within half (load 0)
    int gcol = ((tid & 7) ^ (r0 & 7)) * 8;          // bf16 col within 64-k tile

    int koff0 = (hi * 16) ^ ((lr & 7) << 4);
    int koff1 = (64 + hi * 16) ^ ((lr & 7) << 4);
    int arow[8], brow[4];
#pragma unroll
    for (int m = 0; m < 8; ++m) arow[m] = (wr * 128 + m * 16 + lr) * 128;
#pragma unroll
    for (int n = 0; n < 4; ++n) brow[n] = (wc * 64 + n * 16 + lr) * 128;

    f32x4 acc[8][4] = {};
    short8 aF[4][2], bF[4][2];
    const char* Ac = (const char*)As;
    const char* Bc = (const char*)Bs;

    auto stage = [&](const short* Gb, char* Lb, int tau, int hf) {
        const short* g0 = Gb + (size_t)(hf * 128 + r0) * K + tau * 64 + gcol;
        char* l = Lb + (tau & 1) * 32768 + hf * 16384;
        gload_lds16(g0, l + tid * 16);
        gload_lds16(g0 + (size_t)64 * K, l + (tid + 512) * 16);
    };
    auto lda4 = [&](const char* base, int roff) {
#pragma unroll
        for (int m = 0; m < 4; ++m) {
            aF[m][0] = *(const short8*)(base + arow[roff + m] + koff0);
            aF[m][1] = *(const short8*)(base + arow[roff + m] + koff1);
        }
    };
    auto ldb2 = [&](const char* base, int noff) {
#pragma unroll
        for (int n = 0; n < 2; ++n) {
            bF[noff + n][0] = *(const short8*)(base + brow[noff + n] + koff0);
            bF[noff + n][1] = *(const short8*)(base + brow[noff + n] + koff1);
        }
    };

#define MFMA_QUAD(MOFF, NOFF)                                                          \
    __builtin_amdgcn_s_setprio(1);                                                     \
    _Pragma("unroll") for (int m = 0; m < 4; ++m) {                                    \
        _Pragma("unroll") for (int n = 0; n < 2; ++n) {                                \
            acc[MOFF + m][NOFF + n] = __builtin_amdgcn_mfma_f32_16x16x32_bf16(         \
                aF[m][0], bF[NOFF + n][0], acc[MOFF + m][NOFF + n], 0, 0, 0);          \
            acc[MOFF + m][NOFF + n] = __builtin_amdgcn_mfma_f32_16x16x32_bf16(         \
                aF[m][1], bF[NOFF + n][1], acc[MOFF + m][NOFF + n], 0, 0, 0);          \
        }                                                                              \
    }                                                                                  \
    __builtin_amdgcn_s_setprio(0);

    int NK = K >> 6;
    stage(Ab, (char*)As, 0, 0); stage(Ab, (char*)As, 0, 1);
    stage(Bb, (char*)Bs, 0, 0); stage(Bb, (char*)Bs, 0, 1);
    stage(Ab, (char*)As, 1, 0); stage(Ab, (char*)As, 1, 1);
    stage(Bb, (char*)Bs, 1, 0); stage(Bb, (char*)Bs, 1, 1);
    asm volatile("s_waitcnt vmcnt(0)" ::: "memory");
    BAR();

    int niters = NK >> 1;
    for (int it = 0; it < niters; ++it) {
        bool st = it < niters - 1;
        int u2 = 2 * it + 2, v2 = 2 * it + 3;
        const char* a0 = Ac;            const char* b0 = Bc;
        const char* a1 = Ac + 32768;    const char* b1 = Bc + 32768;

        // ===== tile u (buf0), phases 1-4 =====
        lda4(a0, 0); ldb2(b0, 0);
        BAR();
        MFMA_QUAD(0, 0);
        BAR();
        ldb2(b0, 2);
        BAR();
        MFMA_QUAD(0, 2);
        BAR();
        lda4(a0, 4);
        if (st) stage(Bb, (char*)Bs, u2, 0);
        BAR();
        MFMA_QUAD(4, 0);
        BAR();
        if (st) stage(Bb, (char*)Bs, u2, 1);
        BAR();
        MFMA_QUAD(4, 2);
        asm volatile("s_waitcnt vmcnt(4)" ::: "memory");
        BAR();

        // ===== tile v (buf1), phases 5-8 =====
        lda4(a1, 0); ldb2(b1, 0);
        if (st) stage(Ab, (char*)As, u2, 0);
        BAR();
        MFMA_QUAD(0, 0);
        BAR();
        ldb2(b1, 2);
        if (st) stage(Ab, (char*)As, u2, 1);
        BAR();
        MFMA_QUAD(0, 2);
        BAR();
        lda4(a1, 4);
        if (st) stage(Bb, (char*)Bs, v2, 0);
        BAR();
        MFMA_QUAD(4, 0);
        BAR();
        if (st) { stage(Bb, (char*)Bs, v2, 1); stage(Ab, (char*)As, v2, 0); stage(Ab, (char*)As, v2, 1); }
        BAR();
        MFMA_QUAD(4, 2);
        asm volatile("s_waitcnt vmcnt(8)" ::: "memory");
        BAR();
    }

    int crow = rp * 256 + wr * 128 + hi * 4;
    int ccol = cp * 256 + wc * 64 + lr;
#pragma unroll
    for (int m = 0; m < 8; ++m)
#pragma unroll
        for (int n = 0; n < 4; ++n) {
#pragma unroll
            for (int j = 0; j < 4; ++j)
                C[(size_t)(crow + m * 16 + j) * N + ccol + n * 16] = acc[m][n][j];
        }
#undef MFMA_QUAD
}

// ---------------- flash attention ----------------
__global__ __launch_bounds__(256) void k_attn(const short* __restrict__ q,
                                              const short* __restrict__ k,
                                              const short* __restrict__ vT,
                                              short* __restrict__ out) {
    int qt = blockIdx.x, head = blockIdx.y, b = blockIdx.z;
    int qbase = qt * 64;
    __shared__ short Qs[64][72];
    __shared__ short Ps[4][16][72];
    int tid = threadIdx.x, lane = tid & 63, w = tid >> 6;
    int lr = lane & 15, lg4 = (lane >> 4) * 4, lk8 = (lane >> 4) * 8;

#pragma unroll
    for (int c = 0; c < 2; ++c) {
        int chunk = tid + 256 * c;
        int row = chunk >> 3, h8 = (chunk & 7) * 8;
        *(short8*)&Qs[row][h8] =
            *(const short8*)&q[(size_t)(b * T_ + qbase + row) * H_ + head * HD_ + h8];
    }
    __syncthreads();

    short8 qf[2];
    qf[0] = *(short8*)&Qs[w * 16 + lr][lk8];
    qf[1] = *(short8*)&Qs[w * 16 + lr][32 + lk8];

    f32x4 o[4] = {};
    float m[4] = {-1e30f, -1e30f, -1e30f, -1e30f};
    float lsum[4] = {0.f, 0.f, 0.f, 0.f};

    for (int kt = 0; kt <= qt; ++kt) {
        int kb = kt * 64;
        f32x4 s[4] = {};
#pragma unroll
        for (int ks = 0; ks < 2; ++ks) {
#pragma unroll
            for (int f = 0; f < 4; ++f) {
                short8 kf = *(const short8*)&k[(size_t)(b * T_ + kb + f * 16 + lr) * H_ +
                                               head * HD_ + ks * 32 + lk8];
                s[f] = __builtin_amdgcn_mfma_f32_16x16x32_bf16(qf[ks], kf, s[f], 0, 0, 0);
            }
        }
        if (kt == qt) {
#pragma unroll
            for (int f = 0; f < 4; ++f) {
                int key = kb + f * 16 + lr;
#pragma unroll
                for (int j = 0; j < 4; ++j) {
                    int qrow = qbase + w * 16 + lg4 + j;
                    if (key > qrow) s[f][j] = -1e30f;
                }
            }
        }
#pragma unroll
        for (int j = 0; j < 4; ++j) {
            float mx = fmaxf(fmaxf(s[0][j], s[1][j]), fmaxf(s[2][j], s[3][j]));
#pragma unroll
            for (int off = 1; off < 16; off <<= 1) mx = fmaxf(mx, __shfl_xor(mx, off, 64));
            float mnew = fmaxf(m[j], mx);
            float sc = __expf(m[j] - mnew);
            m[j] = mnew;
            float rs = 0.f;
#pragma unroll
            for (int f = 0; f < 4; ++f) {
                float p = __expf(s[f][j] - mnew);
                s[f][j] = p;
                rs += p;
            }
#pragma unroll
            for (int off = 1; off < 16; off <<= 1) rs += __shfl_xor(rs, off, 64);
            lsum[j] = lsum[j] * sc + rs;
#pragma unroll
            for (int f = 0; f < 4; ++f) o[f][j] *= sc;
#pragma unroll
            for (int f = 0; f < 4; ++f) Ps[w][lg4 + j][f * 16 + lr] = f2bf(s[f][j]);
        }
#pragma unroll
        for (int ks2 = 0; ks2 < 2; ++ks2) {
            short8 pf = *(short8*)&Ps[w][lr][ks2 * 32 + lk8];
            __builtin_amdgcn_s_setprio(1);
#pragma unroll
            for (int f = 0; f < 4; ++f) {
                short8 vf = *(const short8*)&vT[((size_t)(b * HEADS_ + head) * HD_ + f * 16 + lr) * T_ +
                                                kb + ks2 * 32 + lk8];
                o[f] = __builtin_amdgcn_mfma_f32_16x16x32_bf16(pf, vf, o[f], 0, 0, 0);
            }
            __builtin_amdgcn_s_setprio(0);
        }
    }
#pragma unroll
    for (int f = 0; f < 4; ++f)
#pragma unroll
        for (int j = 0; j < 4; ++j) {
            float val = o[f][j] / lsum[j];
            out[(size_t)(b * T_ + qbase + w * 16 + lg4 + j) * H_ + head * HD_ + f * 16 + lr] =
                f2bf(val);
        }
}

// ---------------- launch ----------------
extern "C" void kernel_launch(void* const* d_in, const int* in_sizes, int n_in,
                              void* d_out, int out_size, void* d_ws, size_t ws_size,
                              hipStream_t stream) {
    const float* prefix = (const float*)d_in[0];
    const int* ids = (const int*)d_in[1];
    const float* emb = (const float*)d_in[2];
    const float* Wq = (const float*)d_in[3];
    const float* Wk = (const float*)d_in[4];
    const float* Wv = (const float*)d_in[5];
    const float* Wo = (const float*)d_in[6];
    const float* g1 = (const float*)d_in[7];
    const float* b1 = (const float*)d_in[8];
    const float* g2 = (const float*)d_in[9];
    const float* b2 = (const float*)d_in[10];
    const float* W1 = (const float*)d_in[11];
    const float* bm1 = (const float*)d_in[12];
    const float* W2 = (const float*)d_in[13];
    const float* bm2 = (const float*)d_in[14];
    const float* gf = (const float*)d_in[15];
    const float* bf = (const float*)d_in[16];
    const float* Whead = (const float*)d_in[17];
    float* out = (float*)d_out;

    char* wsp = (char*)d_ws;
    float* x = (float*)wsp;   wsp += (size_t)BT_ * H_ * 4;
    float* p = (float*)wsp;   wsp += (size_t)2 * BT_ * H_ * 4;   // split-K slabs
    short* h = (short*)wsp;   wsp += (size_t)BT_ * H_ * 2;
    short* qb = (short*)wsp;  wsp += (size_t)BT_ * H_ * 2;
    short* kb = (short*)wsp;  wsp += (size_t)BT_ * H_ * 2;
    short* vT = (short*)wsp;  wsp += (size_t)BT_ * H_ * 2;
    short* ao = (short*)wsp;  wsp += (size_t)BT_ * H_ * 2;
    short* mid = (short*)wsp; wsp += (size_t)BT_ * F_ * 2;
    short* WqkvT = (short*)wsp; wsp += (size_t)NL_ * 3 * H_ * H_ * 2;
    short* WoT = (short*)wsp;   wsp += (size_t)NL_ * H_ * H_ * 2;
    short* W1T = (short*)wsp;   wsp += (size_t)NL_ * H_ * F_ * 2;
    short* W2T = (short*)wsp;   wsp += (size_t)NL_ * F_ * H_ * 2;
    short* WhT = (short*)wsp;   wsp += (size_t)H_ * V_ * 2;

    dim3 blk(256);
    k_cvt_all<<<dim3(56576), blk, 0, stream>>>(Wq, Wk, Wv, Wo, W1, W2, Whead,
                                               WqkvT, WoT, W1T, W2T, WhT);
    k_embed_ln<<<BT_, blk, 0, stream>>>(prefix, ids, emb, g1, b1, x, h);
    for (int l = 0; l < NL_; ++l) {
        size_t o1 = (size_t)l * H_ * H_;
        size_t oq = (size_t)l * 3 * H_ * H_;
        size_t o2 = (size_t)l * H_ * F_;
        k_gemm<3, false, false, false><<<dim3(576), blk, 0, stream>>>(
            h, WqkvT + oq, nullptr, qb, kb, vT, BT_, 3 * H_, H_, 1.f);
        k_attn<<<dim3(T_ / 64, HEADS_, B_), blk, 0, stream>>>(qb, kb, vT, ao);
        // Wo: split-K x2 -> p slabs; combine fused into k_add_ln
        k_gemm<0, false, false, true><<<dim3(384), blk, 0, stream>>>(
            ao, WoT + o1, nullptr, p, nullptr, nullptr, BT_, H_, H_, 1.f);
        k_add_ln<<<BT_, blk, 0, stream>>>(x, p, p + (size_t)BT_ * H_,
                                          g2 + l * H_, b2 + l * H_, h);
        k_gemm<1, true, true, false><<<dim3(768), blk, 0, stream>>>(
            h, W1T + o2, bm1 + (size_t)l * F_, mid, nullptr, nullptr, BT_, F_, H_, 1.f);
        // W2: split-K x2 -> p slabs
        k_gemm<0, true, false, true><<<dim3(384), blk, 0, stream>>>(
            mid, W2T + o2, bm2 + (size_t)l * H_, p, nullptr, nullptr, BT_, H_, F_, 1.f);
        const float* gn = (l + 1 < NL_) ? g1 + (l + 1) * H_ : gf;
        const float* bn = (l + 1 < NL_) ? b1 + (l + 1) * H_ : bf;
        k_add_ln<<<BT_, blk, 0, stream>>>(x, p, p + (size_t)BT_ * H_, gn, bn, h);
    }
    k_gemm8<<<dim3((BT_ / 256) * (V_ / 256)), dim3(512), 0, stream>>>(
        h, WhT, out, BT_, V_, H_);
}

// Round 9
// 980.312 us; speedup vs baseline: 2.7687x; 1.0374x over previous
//
#include <hip/hip_runtime.h>
#include <stdint.h>

#define B_ 2
#define P_ 256
#define TL_ 1280
#define T_ 1536
#define H_ 1024
#define HEADS_ 16
#define HD_ 64
#define NL_ 2
#define V_ 32000
#define F_ 4096
#define BT_ (B_ * T_)

typedef __attribute__((ext_vector_type(4))) float f32x4;
typedef __attribute__((ext_vector_type(8))) short short8;
typedef __attribute__((ext_vector_type(4))) short short4v;

typedef __attribute__((address_space(3))) uint32_t lds_u32_t;
typedef const __attribute__((address_space(1))) uint32_t glb_u32_t;

__device__ inline void gload_lds16(const void* g, void* l) {
    __builtin_amdgcn_global_load_lds((glb_u32_t*)g, (lds_u32_t*)l, 16, 0, 0);
}

__device__ inline short f2bf(float f) {
    union { float f; unsigned u; } v; v.f = f;
    unsigned r = v.u + 0x7FFF + ((v.u >> 16) & 1);
    return (short)(r >> 16);
}

#define BAR() asm volatile("s_barrier" ::: "memory")
#define WAIT_VM0() asm volatile("s_waitcnt vmcnt(0)" ::: "memory")
#define WAIT_VM4() asm volatile("s_waitcnt vmcnt(4)" ::: "memory")
#define WAIT_VM8() asm volatile("s_waitcnt vmcnt(8)" ::: "memory")

// ---------------- fused weight transpose-convert: f32 [K,N] -> bf16 [N,K] ----
__global__ __launch_bounds__(256) void k_cvt_all(
    const float* __restrict__ Wq, const float* __restrict__ Wk,
    const float* __restrict__ Wv, const float* __restrict__ Wo,
    const float* __restrict__ W1, const float* __restrict__ W2,
    const float* __restrict__ Wh,
    short* __restrict__ WqkvT, short* __restrict__ WoT,
    short* __restrict__ W1T, short* __restrict__ W2T, short* __restrict__ WhT) {
    int id = blockIdx.x;
    const float* src;
    short* dst;
    int K, N;
    float scale = 1.f;
    if (id < 6144) {                       // qkv: 2 layers x 3 mats x 1024 tiles
        int mat = id >> 10;
        int tile = id & 1023;
        int l = mat / 3, which = mat - l * 3;
        src = (which == 0 ? Wq : which == 1 ? Wk : Wv) + (size_t)l * H_ * H_;
        dst = WqkvT + (size_t)(l * 3 + which) * H_ * H_;
        K = H_; N = H_;
        if (which == 0) scale = 0.125f;
        id = tile;
    } else if (id < 8192) {                // wo
        int rel = id - 6144;
        int l = rel >> 10;
        src = Wo + (size_t)l * H_ * H_;
        dst = WoT + (size_t)l * H_ * H_;
        K = H_; N = H_;
        id = rel & 1023;
    } else if (id < 16384) {               // w1: K=H, N=F
        int rel = id - 8192;
        int l = rel >> 12;
        src = W1 + (size_t)l * H_ * F_;
        dst = W1T + (size_t)l * H_ * F_;
        K = H_; N = F_;
        id = rel & 4095;
    } else if (id < 24576) {               // w2: K=F, N=H
        int rel = id - 16384;
        int l = rel >> 12;
        src = W2 + (size_t)l * F_ * H_;
        dst = W2T + (size_t)l * F_ * H_;
        K = F_; N = H_;
        id = rel & 4095;
    } else {                               // head: K=H, N=V
        id -= 24576;
        src = Wh; dst = WhT;
        K = H_; N = V_;
    }
    int ntn = N >> 5;
    int nb = (id % ntn) * 32, kb = (id / ntn) * 32;

    __shared__ float ts[32][36];
    int tid = threadIdx.x;
    int r = tid >> 3, c4 = (tid & 7) * 4;
    f32x4 v = *(const f32x4*)&src[(size_t)(kb + r) * N + nb + c4];
    *(f32x4*)&ts[r][c4] = v;
    __syncthreads();
    int wn = tid >> 3, wk4 = (tid & 7) * 4;
    short o[4];
#pragma unroll
    for (int j = 0; j < 4; ++j) o[j] = f2bf(ts[wk4 + j][wn] * scale);
    *(short4v*)&dst[(size_t)(nb + wn) * K + kb + wk4] = *(short4v*)o;
}

// ---------------- embed + concat + first layernorm ---------------------------
__global__ __launch_bounds__(256) void k_embed_ln(const float* __restrict__ prefix,
                                                  const int* __restrict__ ids,
                                                  const float* __restrict__ emb,
                                                  const float* __restrict__ g,
                                                  const float* __restrict__ b,
                                                  float* __restrict__ x,
                                                  short* __restrict__ h) {
    int r = blockIdx.x;
    int bb = r / T_, t = r % T_;
    const float* src = (t < P_) ? (prefix + (size_t)(bb * P_ + t) * H_)
                                : (emb + (size_t)ids[bb * TL_ + (t - P_)] * H_);
    int tid = threadIdx.x;
    f32x4 v = *(const f32x4*)&src[tid * 4];
    *(f32x4*)&x[(size_t)r * H_ + tid * 4] = v;
    float s = v[0] + v[1] + v[2] + v[3];
    float sq = v[0] * v[0] + v[1] * v[1] + v[2] * v[2] + v[3] * v[3];
#pragma unroll
    for (int off = 32; off; off >>= 1) {
        s += __shfl_down(s, off, 64);
        sq += __shfl_down(sq, off, 64);
    }
    __shared__ float red[10];
    int wid = tid >> 6;
    if ((tid & 63) == 0) { red[wid] = s; red[4 + wid] = sq; }
    __syncthreads();
    if (tid == 0) {
        float S = red[0] + red[1] + red[2] + red[3];
        float SQ = red[4] + red[5] + red[6] + red[7];
        float mu = S * (1.0f / H_);
        float var = SQ * (1.0f / H_) - mu * mu;
        red[8] = mu;
        red[9] = rsqrtf(var + 1e-5f);
    }
    __syncthreads();
    float mu = red[8], rstd = red[9];
    short o[4];
#pragma unroll
    for (int j = 0; j < 4; ++j)
        o[j] = f2bf((v[j] - mu) * rstd * g[tid * 4 + j] + b[tid * 4 + j]);
    *(short4v*)&h[(size_t)r * H_ + tid * 4] = *(short4v*)o;
}

// ---------------- x += p0 + p1 (split-K combine), then layernorm -> bf16 -----
__global__ __launch_bounds__(256) void k_add_ln(float* __restrict__ x,
                                                const float* __restrict__ p0,
                                                const float* __restrict__ p1,
                                                const float* __restrict__ g,
                                                const float* __restrict__ b,
                                                short* __restrict__ out) {
    int r = blockIdx.x;
    int tid = threadIdx.x;
    size_t base = (size_t)r * H_ + tid * 4;
    f32x4 v = *(f32x4*)&x[base];
    f32x4 a0 = *(const f32x4*)&p0[base];
    f32x4 a1 = *(const f32x4*)&p1[base];
#pragma unroll
    for (int j = 0; j < 4; ++j) v[j] += a0[j] + a1[j];
    *(f32x4*)&x[base] = v;
    float s = v[0] + v[1] + v[2] + v[3];
    float sq = v[0] * v[0] + v[1] * v[1] + v[2] * v[2] + v[3] * v[3];
#pragma unroll
    for (int off = 32; off; off >>= 1) {
        s += __shfl_down(s, off, 64);
        sq += __shfl_down(sq, off, 64);
    }
    __shared__ float red[10];
    int wid = tid >> 6;
    if ((tid & 63) == 0) { red[wid] = s; red[4 + wid] = sq; }
    __syncthreads();
    if (tid == 0) {
        float S = red[0] + red[1] + red[2] + red[3];
        float SQ = red[4] + red[5] + red[6] + red[7];
        float mu = S * (1.0f / H_);
        float var = SQ * (1.0f / H_) - mu * mu;
        red[8] = mu;
        red[9] = rsqrtf(var + 1e-5f);
    }
    __syncthreads();
    float mu = red[8], rstd = red[9];
    short o[4];
#pragma unroll
    for (int j = 0; j < 4; ++j)
        o[j] = f2bf((v[j] - mu) * rstd * g[tid * 4 + j] + b[tid * 4 + j]);
    *(short4v*)&out[base] = *(short4v*)o;
}

// ---------------- 128x128 GEMM, BK=32, QUAD-buffered, prefetch depth 3 -------
template <int STORE, bool HAS_BIAS, bool SILU, bool KSPLIT>
__global__ __launch_bounds__(256) void k_gemm(const short* __restrict__ A,
                                              const short* __restrict__ Bt,
                                              const float* __restrict__ bias,
                                              void* __restrict__ outp,
                                              void* __restrict__ outp2,
                                              void* __restrict__ outp3,
                                              int M, int N, int K, float alpha) {
    __shared__ short As[4][128 * 32];
    __shared__ short Bs[4][128 * 32];
    int tid = threadIdx.x;
    int lane = tid & 63, w = tid >> 6;
    int wr = w >> 1, wc = w & 1;
    int nwg = gridDim.x;
    int mblocks = M >> 7;
    int cpx = nwg >> 3;
    int logical = (blockIdx.x & 7) * cpx + (blockIdx.x >> 3);
    int ks = 0;
    if (KSPLIT) {
        int half = mblocks * (N >> 7);
        if (logical >= half) { ks = 1; logical -= half; }
    }
    int rp = logical % mblocks, cp = logical / mblocks;
    int mbase = rp * 128, nbase = cp * 128;
    int Kh = KSPLIT ? (K >> 1) : K;
    int lr = lane & 15, hi = lane >> 4;
    int lg = hi * 4;

    f32x4 acc[4][4] = {};

    int r0 = tid >> 2;
    int gcol = ((tid & 3) ^ (r0 & 3)) * 8;
    const short* Ab = A + (size_t)mbase * K + (size_t)ks * Kh;
    const short* Bb = Bt + (size_t)nbase * K + (size_t)ks * Kh;

    int koff = ((hi ^ (lr & 3)) << 4);
    int arow[4], brow[4];
#pragma unroll
    for (int m = 0; m < 4; ++m) arow[m] = (wr * 64 + m * 16 + lr) * 64;
#pragma unroll
    for (int n = 0; n < 4; ++n) brow[n] = (wc * 64 + n * 16 + lr) * 64;

    auto stage = [&](int t, int buf) {
        const short* ga = Ab + (size_t)r0 * K + t * 32 + gcol;
        const short* gb = Bb + (size_t)r0 * K + t * 32 + gcol;
        char* la = (char*)&As[buf][0];
        char* lb = (char*)&Bs[buf][0];
        gload_lds16(ga, la + tid * 16);
        gload_lds16(ga + (size_t)64 * K, la + tid * 16 + 4096);
        gload_lds16(gb, lb + tid * 16);
        gload_lds16(gb + (size_t)64 * K, lb + tid * 16 + 4096);
    };

    int NT = Kh >> 5;
    stage(0, 0);
    stage(1, 1);
    stage(2, 2);
    WAIT_VM8();
    BAR();

    for (int t = 0; t < NT; ++t) {
        bool iss = (t + 3 < NT);
        if (iss) stage(t + 3, (t + 3) & 3);
        const char* a = (const char*)&As[t & 3][0];
        const char* b = (const char*)&Bs[t & 3][0];
        short8 af[4], bfr[4];
#pragma unroll
        for (int mi = 0; mi < 4; ++mi) af[mi] = *(const short8*)(a + arow[mi] + koff);
#pragma unroll
        for (int ni = 0; ni < 4; ++ni) bfr[ni] = *(const short8*)(b + brow[ni] + koff);
        __builtin_amdgcn_s_setprio(1);
#pragma unroll
        for (int mi = 0; mi < 4; ++mi)
#pragma unroll
            for (int ni = 0; ni < 4; ++ni)
                acc[mi][ni] = __builtin_amdgcn_mfma_f32_16x16x32_bf16(af[mi], bfr[ni], acc[mi][ni], 0, 0, 0);
        __builtin_amdgcn_s_setprio(0);
        if (t + 1 < NT) {
            if (iss) WAIT_VM8();
            else if (t + 2 < NT) WAIT_VM4();
            else WAIT_VM0();
            BAR();
        }
    }

#pragma unroll
    for (int ni = 0; ni < 4; ++ni) {
        int col = nbase + wc * 64 + ni * 16 + lr;
        float bv = (HAS_BIAS && ks == 0) ? bias[col] : 0.f;
#pragma unroll
        for (int mi = 0; mi < 4; ++mi) {
#pragma unroll
            for (int j = 0; j < 4; ++j) {
                int row = mbase + wr * 64 + mi * 16 + lg + j;
                float vv = acc[mi][ni][j] * alpha + bv;
                if (SILU) vv = vv / (1.f + __expf(-vv));
                if (STORE == 0) {
                    ((float*)outp)[(size_t)ks * M * N + (size_t)row * N + col] = vv;
                } else if (STORE == 1) {
                    ((short*)outp)[(size_t)row * N + col] = f2bf(vv);
                } else {  // STORE == 3: fused QKV
                    int seg = col >> 10;
                    int c = col & 1023;
                    if (seg == 0) {
                        ((short*)outp)[(size_t)row * H_ + c] = f2bf(vv);
                    } else if (seg == 1) {
                        ((short*)outp2)[(size_t)row * H_ + c] = f2bf(vv);
                    } else {
                        int bb = row / T_, t2 = row % T_;
                        ((short*)outp3)[((size_t)(bb * HEADS_ + (c >> 6)) * HD_ + (c & 63)) * T_ + t2] = f2bf(vv);
                    }
                }
            }
        }
    }
}

// ---------------- 8-phase 256x256 GEMM, PERSISTENT (grid 256) ----------------
// Round-8 hardening after the round-7 determinism failure:
//  - plain C stores (nontemporal_store coherence on gfx950 is unverified;
//    the re-poisoned d_out + replay comparison is exactly where weak stores
//    would show up)
//  - tail fix: final K-iteration (st==false) drains vmcnt to 0 at ph4/ph8 —
//    with no new stages issued, the old vmcnt(4) left tile-v's A-half loads
//    outstanding while ph5 ds_read them (latent race carried since round 2).
// Persistent chunking + boundary overlap retained: epilogue stores and next
// tile's prologue loads are in flight together, then one vmcnt(0)+barrier.
// DO NOT cap registers below 256/wave (round-3 post-mortem: spills, 7.5x slow).
__global__ __launch_bounds__(512, 2) void k_gemm8(const short* __restrict__ A,
                                                  const short* __restrict__ Bt,
                                                  float* __restrict__ C,
                                                  int M, int N, int K) {
    __shared__ short As[2 * 256 * 64];   // 64 KiB
    __shared__ short Bs[2 * 256 * 64];   // 64 KiB
    int tid = threadIdx.x;
    int lane = tid & 63, w = tid >> 6;
    int wr = w >> 2, wc = w & 3;
    int lr = lane & 15, hi = lane >> 4;

    int mtiles = M >> 8;
    int total = mtiles * (N >> 8);
    // persistent chunking: grid MUST be 256. XCD x owns blocks g in [32x,32x+31]
    int g = ((blockIdx.x & 7) << 5) + (blockIdx.x >> 3);
    int qq = total >> 8, rr = total & 255;
    int start = g * qq + (g < rr ? g : rr);
    int cnt = qq + (g < rr ? 1 : 0);

    int r0 = tid >> 3;
    int gcol = ((tid & 7) ^ (r0 & 7)) * 8;
    int koff0 = (hi * 16) ^ ((lr & 7) << 4);
    int koff1 = (64 + hi * 16) ^ ((lr & 7) << 4);
    int arow[8], brow[4];
#pragma unroll
    for (int m = 0; m < 8; ++m) arow[m] = (wr * 128 + m * 16 + lr) * 128;
#pragma unroll
    for (int n = 0; n < 4; ++n) brow[n] = (wc * 64 + n * 16 + lr) * 128;

    f32x4 acc[8][4];
    short8 aF[4][2], bF[4][2];
    const char* Ac = (const char*)As;
    const char* Bc = (const char*)Bs;

    auto stage = [&](const short* Gb, char* Lb, int tau, int hf) {
        const short* g0 = Gb + (size_t)(hf * 128 + r0) * K + tau * 64 + gcol;
        char* l = Lb + (tau & 1) * 32768 + hf * 16384;
        gload_lds16(g0, l + tid * 16);
        gload_lds16(g0 + (size_t)64 * K, l + (tid + 512) * 16);
    };
    auto prolog = [&](const short* Ab, const short* Bb) {
        stage(Ab, (char*)As, 0, 0); stage(Ab, (char*)As, 0, 1);
        stage(Bb, (char*)Bs, 0, 0); stage(Bb, (char*)Bs, 0, 1);
        stage(Ab, (char*)As, 1, 0); stage(Ab, (char*)As, 1, 1);
        stage(Bb, (char*)Bs, 1, 0); stage(Bb, (char*)Bs, 1, 1);
    };
    auto lda4 = [&](const char* base, int roff) {
#pragma unroll
        for (int m = 0; m < 4; ++m) {
            aF[m][0] = *(const short8*)(base + arow[roff + m] + koff0);
            aF[m][1] = *(const short8*)(base + arow[roff + m] + koff1);
        }
    };
    auto ldb2 = [&](const char* base, int noff) {
#pragma unroll
        for (int n = 0; n < 2; ++n) {
            bF[noff + n][0] = *(const short8*)(base + brow[noff + n] + koff0);
            bF[noff + n][1] = *(const short8*)(base + brow[noff + n] + koff1);
        }
    };

#define MFMA_QUAD(MOFF, NOFF)                                                          \
    __builtin_amdgcn_s_setprio(1);                                                     \
    _Pragma("unroll") for (int m = 0; m < 4; ++m) {                                    \
        _Pragma("unroll") for (int n = 0; n < 2; ++n) {                                \
            acc[MOFF + m][NOFF + n] = __builtin_amdgcn_mfma_f32_16x16x32_bf16(         \
                aF[m][0], bF[NOFF + n][0], acc[MOFF + m][NOFF + n], 0, 0, 0);          \
            acc[MOFF + m][NOFF + n] = __builtin_amdgcn_mfma_f32_16x16x32_bf16(         \
                aF[m][1], bF[NOFF + n][1], acc[MOFF + m][NOFF + n], 0, 0, 0);          \
        }                                                                              \
    }                                                                                  \
    __builtin_amdgcn_s_setprio(0);

    int NK = K >> 6;
    int niters = NK >> 1;

    for (int i = 0; i < cnt; ++i) {
        int t0 = start + i;
        int rp = t0 % mtiles, cp = t0 / mtiles;
        const short* Ab = A + (size_t)rp * 256 * K;
        const short* Bb = Bt + (size_t)cp * 256 * K;
        f32x4 zz = {0.f, 0.f, 0.f, 0.f};
#pragma unroll
        for (int m = 0; m < 8; ++m)
#pragma unroll
            for (int n = 0; n < 4; ++n) acc[m][n] = zz;

        if (i == 0) {
            prolog(Ab, Bb);
            WAIT_VM0();
            BAR();
        }

        for (int it = 0; it < niters; ++it) {
            bool st = it < niters - 1;
            int u2 = 2 * it + 2, v2 = 2 * it + 3;
            const char* a0 = Ac;            const char* b0 = Bc;
            const char* a1 = Ac + 32768;    const char* b1 = Bc + 32768;

            // ===== tile u (buf0), phases 1-4 =====
            lda4(a0, 0); ldb2(b0, 0);
            BAR();
            MFMA_QUAD(0, 0);
            BAR();
            ldb2(b0, 2);
            BAR();
            MFMA_QUAD(0, 2);
            BAR();
            lda4(a0, 4);
            if (st) stage(Bb, (char*)Bs, u2, 0);
            BAR();
            MFMA_QUAD(4, 0);
            BAR();
            if (st) stage(Bb, (char*)Bs, u2, 1);
            BAR();
            MFMA_QUAD(4, 2);
            if (st) { WAIT_VM4(); } else { WAIT_VM0(); }   // buf1 fully landed
            BAR();

            // ===== tile v (buf1), phases 5-8 =====
            lda4(a1, 0); ldb2(b1, 0);
            if (st) stage(Ab, (char*)As, u2, 0);
            BAR();
            MFMA_QUAD(0, 0);
            BAR();
            ldb2(b1, 2);
            if (st) stage(Ab, (char*)As, u2, 1);
            BAR();
            MFMA_QUAD(0, 2);
            BAR();
            lda4(a1, 4);
            if (st) stage(Bb, (char*)Bs, v2, 0);
            BAR();
            MFMA_QUAD(4, 0);
            BAR();
            if (st) { stage(Bb, (char*)Bs, v2, 1); stage(Ab, (char*)As, v2, 0); stage(Ab, (char*)As, v2, 1); }
            BAR();
            MFMA_QUAD(4, 2);
            if (st) { WAIT_VM8(); } else { WAIT_VM0(); }   // next buf0 landed
            BAR();
        }

        // epilogue (plain stores; all LDS reads of this tile retired pre-BAR)
        int crow = rp * 256 + wr * 128 + hi * 4;
        int ccol = cp * 256 + wc * 64 + lr;
#pragma unroll
        for (int m = 0; m < 8; ++m)
#pragma unroll
            for (int n = 0; n < 4; ++n) {
#pragma unroll
                for (int j = 0; j < 4; ++j)
                    C[(size_t)(crow + m * 16 + j) * N + ccol + n * 16] = acc[m][n][j];
            }

        if (i + 1 < cnt) {
            // boundary overlap: prologue loads fly while the stores drain
            int t1 = t0 + 1;
            int rp1 = t1 % mtiles, cp1 = t1 / mtiles;
            prolog(A + (size_t)rp1 * 256 * K, Bt + (size_t)cp1 * 256 * K);
            WAIT_VM0();
            BAR();
        }
    }
#undef MFMA_QUAD
}

// ---------------- flash attention ----------------
__global__ __launch_bounds__(256) void k_attn(const short* __restrict__ q,
                                              const short* __restrict__ k,
                                              const short* __restrict__ vT,
                                              short* __restrict__ out) {
    int qt = blockIdx.x, head = blockIdx.y, b = blockIdx.z;
    int qbase = qt * 64;
    __shared__ short Qs[64][72];
    __shared__ short Ps[4][16][72];
    int tid = threadIdx.x, lane = tid & 63, w = tid >> 6;
    int lr = lane & 15, lg4 = (lane >> 4) * 4, lk8 = (lane >> 4) * 8;

#pragma unroll
    for (int c = 0; c < 2; ++c) {
        int chunk = tid + 256 * c;
        int row = chunk >> 3, h8 = (chunk & 7) * 8;
        *(short8*)&Qs[row][h8] =
            *(const short8*)&q[(size_t)(b * T_ + qbase + row) * H_ + head * HD_ + h8];
    }
    __syncthreads();

    short8 qf[2];
    qf[0] = *(short8*)&Qs[w * 16 + lr][lk8];
    qf[1] = *(short8*)&Qs[w * 16 + lr][32 + lk8];

    f32x4 o[4] = {};
    float m[4] = {-1e30f, -1e30f, -1e30f, -1e30f};
    float lsum[4] = {0.f, 0.f, 0.f, 0.f};

    for (int kt = 0; kt <= qt; ++kt) {
        int kb = kt * 64;
        f32x4 s[4] = {};
#pragma unroll
        for (int ks = 0; ks < 2; ++ks) {
#pragma unroll
            for (int f = 0; f < 4; ++f) {
                short8 kf = *(const short8*)&k[(size_t)(b * T_ + kb + f * 16 + lr) * H_ +
                                               head * HD_ + ks * 32 + lk8];
                s[f] = __builtin_amdgcn_mfma_f32_16x16x32_bf16(qf[ks], kf, s[f], 0, 0, 0);
            }
        }
        if (kt == qt) {
#pragma unroll
            for (int f = 0; f < 4; ++f) {
                int key = kb + f * 16 + lr;
#pragma unroll
                for (int j = 0; j < 4; ++j) {
                    int qrow = qbase + w * 16 + lg4 + j;
                    if (key > qrow) s[f][j] = -1e30f;
                }
            }
        }
#pragma unroll
        for (int j = 0; j < 4; ++j) {
            float mx = fmaxf(fmaxf(s[0][j], s[1][j]), fmaxf(s[2][j], s[3][j]));
#pragma unroll
            for (int off = 1; off < 16; off <<= 1) mx = fmaxf(mx, __shfl_xor(mx, off, 64));
            float mnew = fmaxf(m[j], mx);
            float sc = __expf(m[j] - mnew);
            m[j] = mnew;
            float rs = 0.f;
#pragma unroll
            for (int f = 0; f < 4; ++f) {
                float p = __expf(s[f][j] - mnew);
                s[f][j] = p;
                rs += p;
            }
#pragma unroll
            for (int off = 1; off < 16; off <<= 1) rs += __shfl_xor(rs, off, 64);
            lsum[j] = lsum[j] * sc + rs;
#pragma unroll
            for (int f = 0; f < 4; ++f) o[f][j] *= sc;
#pragma unroll
            for (int f = 0; f < 4; ++f) Ps[w][lg4 + j][f * 16 + lr] = f2bf(s[f][j]);
        }
#pragma unroll
        for (int ks2 = 0; ks2 < 2; ++ks2) {
            short8 pf = *(short8*)&Ps[w][lr][ks2 * 32 + lk8];
            __builtin_amdgcn_s_setprio(1);
#pragma unroll
            for (int f = 0; f < 4; ++f) {
                short8 vf = *(const short8*)&vT[((size_t)(b * HEADS_ + head) * HD_ + f * 16 + lr) * T_ +
                                                kb + ks2 * 32 + lk8];
                o[f] = __builtin_amdgcn_mfma_f32_16x16x32_bf16(pf, vf, o[f], 0, 0, 0);
            }
            __builtin_amdgcn_s_setprio(0);
        }
    }
#pragma unroll
    for (int f = 0; f < 4; ++f)
#pragma unroll
        for (int j = 0; j < 4; ++j) {
            float val = o[f][j] / lsum[j];
            out[(size_t)(b * T_ + qbase + w * 16 + lg4 + j) * H_ + head * HD_ + f * 16 + lr] =
                f2bf(val);
        }
}

// ---------------- launch ----------------
extern "C" void kernel_launch(void* const* d_in, const int* in_sizes, int n_in,
                              void* d_out, int out_size, void* d_ws, size_t ws_size,
                              hipStream_t stream) {
    const float* prefix = (const float*)d_in[0];
    const int* ids = (const int*)d_in[1];
    const float* emb = (const float*)d_in[2];
    const float* Wq = (const float*)d_in[3];
    const float* Wk = (const float*)d_in[4];
    const float* Wv = (const float*)d_in[5];
    const float* Wo = (const float*)d_in[6];
    const float* g1 = (const float*)d_in[7];
    const float* b1 = (const float*)d_in[8];
    const float* g2 = (const float*)d_in[9];
    const float* b2 = (const float*)d_in[10];
    const float* W1 = (const float*)d_in[11];
    const float* bm1 = (const float*)d_in[12];
    const float* W2 = (const float*)d_in[13];
    const float* bm2 = (const float*)d_in[14];
    const float* gf = (const float*)d_in[15];
    const float* bf = (const float*)d_in[16];
    const float* Whead = (const float*)d_in[17];
    float* out = (float*)d_out;

    char* wsp = (char*)d_ws;
    float* x = (float*)wsp;   wsp += (size_t)BT_ * H_ * 4;
    float* p = (float*)wsp;   wsp += (size_t)2 * BT_ * H_ * 4;   // split-K slabs
    short* h = (short*)wsp;   wsp += (size_t)BT_ * H_ * 2;
    short* qb = (short*)wsp;  wsp += (size_t)BT_ * H_ * 2;
    short* kb = (short*)wsp;  wsp += (size_t)BT_ * H_ * 2;
    short* vT = (short*)wsp;  wsp += (size_t)BT_ * H_ * 2;
    short* ao = (short*)wsp;  wsp += (size_t)BT_ * H_ * 2;
    short* mid = (short*)wsp; wsp += (size_t)BT_ * F_ * 2;
    short* WqkvT = (short*)wsp; wsp += (size_t)NL_ * 3 * H_ * H_ * 2;
    short* WoT = (short*)wsp;   wsp += (size_t)NL_ * H_ * H_ * 2;
    short* W1T = (short*)wsp;   wsp += (size_t)NL_ * H_ * F_ * 2;
    short* W2T = (short*)wsp;   wsp += (size_t)NL_ * F_ * H_ * 2;
    short* WhT = (short*)wsp;   wsp += (size_t)H_ * V_ * 2;

    dim3 blk(256);
    k_cvt_all<<<dim3(56576), blk, 0, stream>>>(Wq, Wk, Wv, Wo, W1, W2, Whead,
                                               WqkvT, WoT, W1T, W2T, WhT);
    k_embed_ln<<<BT_, blk, 0, stream>>>(prefix, ids, emb, g1, b1, x, h);
    for (int l = 0; l < NL_; ++l) {
        size_t o1 = (size_t)l * H_ * H_;
        size_t oq = (size_t)l * 3 * H_ * H_;
        size_t o2 = (size_t)l * H_ * F_;
        k_gemm<3, false, false, false><<<dim3(576), blk, 0, stream>>>(
            h, WqkvT + oq, nullptr, qb, kb, vT, BT_, 3 * H_, H_, 1.f);
        k_attn<<<dim3(T_ / 64, HEADS_, B_), blk, 0, stream>>>(qb, kb, vT, ao);
        // Wo: split-K x2 -> p slabs; combine fused into k_add_ln
        k_gemm<0, false, false, true><<<dim3(384), blk, 0, stream>>>(
            ao, WoT + o1, nullptr, p, nullptr, nullptr, BT_, H_, H_, 1.f);
        k_add_ln<<<BT_, blk, 0, stream>>>(x, p, p + (size_t)BT_ * H_,
                                          g2 + l * H_, b2 + l * H_, h);
        k_gemm<1, true, true, false><<<dim3(768), blk, 0, stream>>>(
            h, W1T + o2, bm1 + (size_t)l * F_, mid, nullptr, nullptr, BT_, F_, H_, 1.f);
        // W2: split-K x2 -> p slabs
        k_gemm<0, true, false, true><<<dim3(384), blk, 0, stream>>>(
            mid, W2T + o2, bm2 + (size_t)l * H_, p, nullptr, nullptr, BT_, H_, F_, 1.f);
        const float* gn = (l + 1 < NL_) ? g1 + (l + 1) * H_ : gf;
        const float* bn = (l + 1 < NL_) ? b1 + (l + 1) * H_ : bf;
        k_add_ln<<<BT_, blk, 0, stream>>>(x, p, p + (size_t)BT_ * H_, gn, bn, h);
    }
    // head GEMM: persistent 8-phase kernel, grid MUST be 256 (chunk math)
    k_gemm8<<<dim3(256), dim3(512), 0, stream>>>(h, WhT, out, BT_, V_, H_);
}

// Round 10
// 965.606 us; speedup vs baseline: 2.8108x; 1.0152x over previous
//
#include <hip/hip_runtime.h>
#include <stdint.h>

#define B_ 2
#define P_ 256
#define TL_ 1280
#define T_ 1536
#define H_ 1024
#define HEADS_ 16
#define HD_ 64
#define NL_ 2
#define V_ 32000
#define F_ 4096
#define BT_ (B_ * T_)

typedef __attribute__((ext_vector_type(4))) float f32x4;
typedef __attribute__((ext_vector_type(8))) short short8;
typedef __attribute__((ext_vector_type(4))) short short4v;

typedef __attribute__((address_space(3))) uint32_t lds_u32_t;
typedef const __attribute__((address_space(1))) uint32_t glb_u32_t;

__device__ inline void gload_lds16(const void* g, void* l) {
    __builtin_amdgcn_global_load_lds((glb_u32_t*)g, (lds_u32_t*)l, 16, 0, 0);
}

__device__ inline short f2bf(float f) {
    union { float f; unsigned u; } v; v.f = f;
    unsigned r = v.u + 0x7FFF + ((v.u >> 16) & 1);
    return (short)(r >> 16);
}

#define BAR() asm volatile("s_barrier" ::: "memory")
#define WAIT_VM0() asm volatile("s_waitcnt vmcnt(0)" ::: "memory")
#define WAIT_VM4() asm volatile("s_waitcnt vmcnt(4)" ::: "memory")
#define WAIT_VM8() asm volatile("s_waitcnt vmcnt(8)" ::: "memory")

// ---------------- fused weight transpose-convert: f32 [K,N] -> bf16 [N,K] ----
// nt LOADS: the f32 weights are read exactly once per call — keep them from
// polluting L2/L3 (pure replacement hint, no correctness surface).
__global__ __launch_bounds__(256) void k_cvt_all(
    const float* __restrict__ Wq, const float* __restrict__ Wk,
    const float* __restrict__ Wv, const float* __restrict__ Wo,
    const float* __restrict__ W1, const float* __restrict__ W2,
    const float* __restrict__ Wh,
    short* __restrict__ WqkvT, short* __restrict__ WoT,
    short* __restrict__ W1T, short* __restrict__ W2T, short* __restrict__ WhT) {
    int id = blockIdx.x;
    const float* src;
    short* dst;
    int K, N;
    float scale = 1.f;
    if (id < 6144) {                       // qkv: 2 layers x 3 mats x 1024 tiles
        int mat = id >> 10;
        int tile = id & 1023;
        int l = mat / 3, which = mat - l * 3;
        src = (which == 0 ? Wq : which == 1 ? Wk : Wv) + (size_t)l * H_ * H_;
        dst = WqkvT + (size_t)(l * 3 + which) * H_ * H_;
        K = H_; N = H_;
        if (which == 0) scale = 0.125f;
        id = tile;
    } else if (id < 8192) {                // wo
        int rel = id - 6144;
        int l = rel >> 10;
        src = Wo + (size_t)l * H_ * H_;
        dst = WoT + (size_t)l * H_ * H_;
        K = H_; N = H_;
        id = rel & 1023;
    } else if (id < 16384) {               // w1: K=H, N=F
        int rel = id - 8192;
        int l = rel >> 12;
        src = W1 + (size_t)l * H_ * F_;
        dst = W1T + (size_t)l * H_ * F_;
        K = H_; N = F_;
        id = rel & 4095;
    } else if (id < 24576) {               // w2: K=F, N=H
        int rel = id - 16384;
        int l = rel >> 12;
        src = W2 + (size_t)l * F_ * H_;
        dst = W2T + (size_t)l * F_ * H_;
        K = F_; N = H_;
        id = rel & 4095;
    } else {                               // head: K=H, N=V
        id -= 24576;
        src = Wh; dst = WhT;
        K = H_; N = V_;
    }
    int ntn = N >> 5;
    int nb = (id % ntn) * 32, kb = (id / ntn) * 32;

    __shared__ float ts[32][36];
    int tid = threadIdx.x;
    int r = tid >> 3, c4 = (tid & 7) * 4;
    f32x4 v = __builtin_nontemporal_load((const f32x4*)&src[(size_t)(kb + r) * N + nb + c4]);
    *(f32x4*)&ts[r][c4] = v;
    __syncthreads();
    int wn = tid >> 3, wk4 = (tid & 7) * 4;
    short o[4];
#pragma unroll
    for (int j = 0; j < 4; ++j) o[j] = f2bf(ts[wk4 + j][wn] * scale);
    *(short4v*)&dst[(size_t)(nb + wn) * K + kb + wk4] = *(short4v*)o;
}

// ---------------- embed + concat + first layernorm ---------------------------
__global__ __launch_bounds__(256) void k_embed_ln(const float* __restrict__ prefix,
                                                  const int* __restrict__ ids,
                                                  const float* __restrict__ emb,
                                                  const float* __restrict__ g,
                                                  const float* __restrict__ b,
                                                  float* __restrict__ x,
                                                  short* __restrict__ h) {
    int r = blockIdx.x;
    int bb = r / T_, t = r % T_;
    const float* src = (t < P_) ? (prefix + (size_t)(bb * P_ + t) * H_)
                                : (emb + (size_t)ids[bb * TL_ + (t - P_)] * H_);
    int tid = threadIdx.x;
    f32x4 v = *(const f32x4*)&src[tid * 4];
    *(f32x4*)&x[(size_t)r * H_ + tid * 4] = v;
    float s = v[0] + v[1] + v[2] + v[3];
    float sq = v[0] * v[0] + v[1] * v[1] + v[2] * v[2] + v[3] * v[3];
#pragma unroll
    for (int off = 32; off; off >>= 1) {
        s += __shfl_down(s, off, 64);
        sq += __shfl_down(sq, off, 64);
    }
    __shared__ float red[10];
    int wid = tid >> 6;
    if ((tid & 63) == 0) { red[wid] = s; red[4 + wid] = sq; }
    __syncthreads();
    if (tid == 0) {
        float S = red[0] + red[1] + red[2] + red[3];
        float SQ = red[4] + red[5] + red[6] + red[7];
        float mu = S * (1.0f / H_);
        float var = SQ * (1.0f / H_) - mu * mu;
        red[8] = mu;
        red[9] = rsqrtf(var + 1e-5f);
    }
    __syncthreads();
    float mu = red[8], rstd = red[9];
    short o[4];
#pragma unroll
    for (int j = 0; j < 4; ++j)
        o[j] = f2bf((v[j] - mu) * rstd * g[tid * 4 + j] + b[tid * 4 + j]);
    *(short4v*)&h[(size_t)r * H_ + tid * 4] = *(short4v*)o;
}

// ---------------- x += p0+p1+p2+p3 (split-K x4 combine), then LN -> bf16 -----
__global__ __launch_bounds__(256) void k_add_ln(float* __restrict__ x,
                                                const float* __restrict__ p,
                                                const float* __restrict__ g,
                                                const float* __restrict__ b,
                                                short* __restrict__ out) {
    int r = blockIdx.x;
    int tid = threadIdx.x;
    size_t base = (size_t)r * H_ + tid * 4;
    f32x4 v = *(f32x4*)&x[base];
#pragma unroll
    for (int sl = 0; sl < 4; ++sl) {
        f32x4 a = *(const f32x4*)&p[(size_t)sl * BT_ * H_ + base];
#pragma unroll
        for (int j = 0; j < 4; ++j) v[j] += a[j];
    }
    *(f32x4*)&x[base] = v;
    float s = v[0] + v[1] + v[2] + v[3];
    float sq = v[0] * v[0] + v[1] * v[1] + v[2] * v[2] + v[3] * v[3];
#pragma unroll
    for (int off = 32; off; off >>= 1) {
        s += __shfl_down(s, off, 64);
        sq += __shfl_down(sq, off, 64);
    }
    __shared__ float red[10];
    int wid = tid >> 6;
    if ((tid & 63) == 0) { red[wid] = s; red[4 + wid] = sq; }
    __syncthreads();
    if (tid == 0) {
        float S = red[0] + red[1] + red[2] + red[3];
        float SQ = red[4] + red[5] + red[6] + red[7];
        float mu = S * (1.0f / H_);
        float var = SQ * (1.0f / H_) - mu * mu;
        red[8] = mu;
        red[9] = rsqrtf(var + 1e-5f);
    }
    __syncthreads();
    float mu = red[8], rstd = red[9];
    short o[4];
#pragma unroll
    for (int j = 0; j < 4; ++j)
        o[j] = f2bf((v[j] - mu) * rstd * g[tid * 4 + j] + b[tid * 4 + j]);
    *(short4v*)&out[base] = *(short4v*)o;
}

// ---------------- 128x128 GEMM, BK=32, QUAD-buffered, prefetch depth 3 -------
// NSPLIT: K split into NSPLIT slices; grid = NSPLIT x (M/128 x N/128);
// slice ks writes fp32 partials at outp + ks*M*N; bias applied in slice 0.
template <int STORE, bool HAS_BIAS, bool SILU, int NSPLIT>
__global__ __launch_bounds__(256) void k_gemm(const short* __restrict__ A,
                                              const short* __restrict__ Bt,
                                              const float* __restrict__ bias,
                                              void* __restrict__ outp,
                                              void* __restrict__ outp2,
                                              void* __restrict__ outp3,
                                              int M, int N, int K, float alpha) {
    __shared__ short As[4][128 * 32];
    __shared__ short Bs[4][128 * 32];
    int tid = threadIdx.x;
    int lane = tid & 63, w = tid >> 6;
    int wr = w >> 1, wc = w & 1;
    int nwg = gridDim.x;
    int mblocks = M >> 7;
    int cpx = nwg >> 3;
    int logical = (blockIdx.x & 7) * cpx + (blockIdx.x >> 3);
    int ks = 0;
    if (NSPLIT > 1) {
        int per = mblocks * (N >> 7);
        ks = logical / per;
        logical -= ks * per;
    }
    int rp = logical % mblocks, cp = logical / mblocks;
    int mbase = rp * 128, nbase = cp * 128;
    int Kh = K / NSPLIT;
    int lr = lane & 15, hi = lane >> 4;
    int lg = hi * 4;

    f32x4 acc[4][4] = {};

    int r0 = tid >> 2;
    int gcol = ((tid & 3) ^ (r0 & 3)) * 8;
    const short* Ab = A + (size_t)mbase * K + (size_t)ks * Kh;
    const short* Bb = Bt + (size_t)nbase * K + (size_t)ks * Kh;

    int koff = ((hi ^ (lr & 3)) << 4);
    int arow[4], brow[4];
#pragma unroll
    for (int m = 0; m < 4; ++m) arow[m] = (wr * 64 + m * 16 + lr) * 64;
#pragma unroll
    for (int n = 0; n < 4; ++n) brow[n] = (wc * 64 + n * 16 + lr) * 64;

    auto stage = [&](int t, int buf) {
        const short* ga = Ab + (size_t)r0 * K + t * 32 + gcol;
        const short* gb = Bb + (size_t)r0 * K + t * 32 + gcol;
        char* la = (char*)&As[buf][0];
        char* lb = (char*)&Bs[buf][0];
        gload_lds16(ga, la + tid * 16);
        gload_lds16(ga + (size_t)64 * K, la + tid * 16 + 4096);
        gload_lds16(gb, lb + tid * 16);
        gload_lds16(gb + (size_t)64 * K, lb + tid * 16 + 4096);
    };

    int NT = Kh >> 5;
    stage(0, 0);
    stage(1, 1);
    stage(2, 2);
    WAIT_VM8();
    BAR();

    for (int t = 0; t < NT; ++t) {
        bool iss = (t + 3 < NT);
        if (iss) stage(t + 3, (t + 3) & 3);
        const char* a = (const char*)&As[t & 3][0];
        const char* b = (const char*)&Bs[t & 3][0];
        short8 af[4], bfr[4];
#pragma unroll
        for (int mi = 0; mi < 4; ++mi) af[mi] = *(const short8*)(a + arow[mi] + koff);
#pragma unroll
        for (int ni = 0; ni < 4; ++ni) bfr[ni] = *(const short8*)(b + brow[ni] + koff);
        __builtin_amdgcn_s_setprio(1);
#pragma unroll
        for (int mi = 0; mi < 4; ++mi)
#pragma unroll
            for (int ni = 0; ni < 4; ++ni)
                acc[mi][ni] = __builtin_amdgcn_mfma_f32_16x16x32_bf16(af[mi], bfr[ni], acc[mi][ni], 0, 0, 0);
        __builtin_amdgcn_s_setprio(0);
        if (t + 1 < NT) {
            if (iss) WAIT_VM8();
            else if (t + 2 < NT) WAIT_VM4();
            else WAIT_VM0();
            BAR();
        }
    }

#pragma unroll
    for (int ni = 0; ni < 4; ++ni) {
        int col = nbase + wc * 64 + ni * 16 + lr;
        float bv = (HAS_BIAS && ks == 0) ? bias[col] : 0.f;
#pragma unroll
        for (int mi = 0; mi < 4; ++mi) {
#pragma unroll
            for (int j = 0; j < 4; ++j) {
                int row = mbase + wr * 64 + mi * 16 + lg + j;
                float vv = acc[mi][ni][j] * alpha + bv;
                if (SILU) vv = vv / (1.f + __expf(-vv));
                if (STORE == 0) {
                    ((float*)outp)[(size_t)ks * M * N + (size_t)row * N + col] = vv;
                } else if (STORE == 1) {
                    ((short*)outp)[(size_t)row * N + col] = f2bf(vv);
                } else {  // STORE == 3: fused QKV
                    int seg = col >> 10;
                    int c = col & 1023;
                    if (seg == 0) {
                        ((short*)outp)[(size_t)row * H_ + c] = f2bf(vv);
                    } else if (seg == 1) {
                        ((short*)outp2)[(size_t)row * H_ + c] = f2bf(vv);
                    } else {
                        int bb = row / T_, t2 = row % T_;
                        ((short*)outp3)[((size_t)(bb * HEADS_ + (c >> 6)) * HD_ + (c & 63)) * T_ + t2] = f2bf(vv);
                    }
                }
            }
        }
    }
}

// ---------------- 8-phase 256x256 GEMM, PERSISTENT (grid 256) ----------------
// Tail fix retained (final K-iteration drains vmcnt to 0 — the r7 determinism
// failure was this race, not the nt stores).  C stores are nontemporal again:
// on CDNA `nt` is a replacement hint on the coherent L2 path, and keeping the
// 388 MB C stream out of L2/L3 preserves B-panel residency (FETCH 236 MB vs
// 72 MB ideal is C-stream eviction).  If determinism fails this round, nt is
// definitively convicted — revert it and keep everything else.
// DO NOT cap registers below 256/wave (round-3 post-mortem: spills, 7.5x slow).
__global__ __launch_bounds__(512, 2) void k_gemm8(const short* __restrict__ A,
                                                  const short* __restrict__ Bt,
                                                  float* __restrict__ C,
                                                  int M, int N, int K) {
    __shared__ short As[2 * 256 * 64];   // 64 KiB
    __shared__ short Bs[2 * 256 * 64];   // 64 KiB
    int tid = threadIdx.x;
    int lane = tid & 63, w = tid >> 6;
    int wr = w >> 2, wc = w & 3;
    int lr = lane & 15, hi = lane >> 4;

    int mtiles = M >> 8;
    int total = mtiles * (N >> 8);
    int g = ((blockIdx.x & 7) << 5) + (blockIdx.x >> 3);
    int qq = total >> 8, rr = total & 255;
    int start = g * qq + (g < rr ? g : rr);
    int cnt = qq + (g < rr ? 1 : 0);

    int r0 = tid >> 3;
    int gcol = ((tid & 7) ^ (r0 & 7)) * 8;
    int koff0 = (hi * 16) ^ ((lr & 7) << 4);
    int koff1 = (64 + hi * 16) ^ ((lr & 7) << 4);
    int arow[8], brow[4];
#pragma unroll
    for (int m = 0; m < 8; ++m) arow[m] = (wr * 128 + m * 16 + lr) * 128;
#pragma unroll
    for (int n = 0; n < 4; ++n) brow[n] = (wc * 64 + n * 16 + lr) * 128;

    f32x4 acc[8][4];
    short8 aF[4][2], bF[4][2];
    const char* Ac = (const char*)As;
    const char* Bc = (const char*)Bs;

    auto stage = [&](const short* Gb, char* Lb, int tau, int hf) {
        const short* g0 = Gb + (size_t)(hf * 128 + r0) * K + tau * 64 + gcol;
        char* l = Lb + (tau & 1) * 32768 + hf * 16384;
        gload_lds16(g0, l + tid * 16);
        gload_lds16(g0 + (size_t)64 * K, l + (tid + 512) * 16);
    };
    auto prolog = [&](const short* Ab, const short* Bb) {
        stage(Ab, (char*)As, 0, 0); stage(Ab, (char*)As, 0, 1);
        stage(Bb, (char*)Bs, 0, 0); stage(Bb, (char*)Bs, 0, 1);
        stage(Ab, (char*)As, 1, 0); stage(Ab, (char*)As, 1, 1);
        stage(Bb, (char*)Bs, 1, 0); stage(Bb, (char*)Bs, 1, 1);
    };
    auto lda4 = [&](const char* base, int roff) {
#pragma unroll
        for (int m = 0; m < 4; ++m) {
            aF[m][0] = *(const short8*)(base + arow[roff + m] + koff0);
            aF[m][1] = *(const short8*)(base + arow[roff + m] + koff1);
        }
    };
    auto ldb2 = [&](const char* base, int noff) {
#pragma unroll
        for (int n = 0; n < 2; ++n) {
            bF[noff + n][0] = *(const short8*)(base + brow[noff + n] + koff0);
            bF[noff + n][1] = *(const short8*)(base + brow[noff + n] + koff1);
        }
    };

#define MFMA_QUAD(MOFF, NOFF)                                                          \
    __builtin_amdgcn_s_setprio(1);                                                     \
    _Pragma("unroll") for (int m = 0; m < 4; ++m) {                                    \
        _Pragma("unroll") for (int n = 0; n < 2; ++n) {                                \
            acc[MOFF + m][NOFF + n] = __builtin_amdgcn_mfma_f32_16x16x32_bf16(         \
                aF[m][0], bF[NOFF + n][0], acc[MOFF + m][NOFF + n], 0, 0, 0);          \
            acc[MOFF + m][NOFF + n] = __builtin_amdgcn_mfma_f32_16x16x32_bf16(         \
                aF[m][1], bF[NOFF + n][1], acc[MOFF + m][NOFF + n], 0, 0, 0);          \
        }                                                                              \
    }                                                                                  \
    __builtin_amdgcn_s_setprio(0);

    int NK = K >> 6;
    int niters = NK >> 1;

    for (int i = 0; i < cnt; ++i) {
        int t0 = start + i;
        int rp = t0 % mtiles, cp = t0 / mtiles;
        const short* Ab = A + (size_t)rp * 256 * K;
        const short* Bb = Bt + (size_t)cp * 256 * K;
        f32x4 zz = {0.f, 0.f, 0.f, 0.f};
#pragma unroll
        for (int m = 0; m < 8; ++m)
#pragma unroll
            for (int n = 0; n < 4; ++n) acc[m][n] = zz;

        if (i == 0) {
            prolog(Ab, Bb);
            WAIT_VM0();
            BAR();
        }

        for (int it = 0; it < niters; ++it) {
            bool st = it < niters - 1;
            int u2 = 2 * it + 2, v2 = 2 * it + 3;
            const char* a0 = Ac;            const char* b0 = Bc;
            const char* a1 = Ac + 32768;    const char* b1 = Bc + 32768;

            // ===== tile u (buf0), phases 1-4 =====
            lda4(a0, 0); ldb2(b0, 0);
            BAR();
            MFMA_QUAD(0, 0);
            BAR();
            ldb2(b0, 2);
            BAR();
            MFMA_QUAD(0, 2);
            BAR();
            lda4(a0, 4);
            if (st) stage(Bb, (char*)Bs, u2, 0);
            BAR();
            MFMA_QUAD(4, 0);
            BAR();
            if (st) stage(Bb, (char*)Bs, u2, 1);
            BAR();
            MFMA_QUAD(4, 2);
            if (st) { WAIT_VM4(); } else { WAIT_VM0(); }   // buf1 fully landed
            BAR();

            // ===== tile v (buf1), phases 5-8 =====
            lda4(a1, 0); ldb2(b1, 0);
            if (st) stage(Ab, (char*)As, u2, 0);
            BAR();
            MFMA_QUAD(0, 0);
            BAR();
            ldb2(b1, 2);
            if (st) stage(Ab, (char*)As, u2, 1);
            BAR();
            MFMA_QUAD(0, 2);
            BAR();
            lda4(a1, 4);
            if (st) stage(Bb, (char*)Bs, v2, 0);
            BAR();
            MFMA_QUAD(4, 0);
            BAR();
            if (st) { stage(Bb, (char*)Bs, v2, 1); stage(Ab, (char*)As, v2, 0); stage(Ab, (char*)As, v2, 1); }
            BAR();
            MFMA_QUAD(4, 2);
            if (st) { WAIT_VM8(); } else { WAIT_VM0(); }   // next buf0 landed
            BAR();
        }

        // epilogue: nt stores (C never re-read; keep it out of L2/L3)
        int crow = rp * 256 + wr * 128 + hi * 4;
        int ccol = cp * 256 + wc * 64 + lr;
#pragma unroll
        for (int m = 0; m < 8; ++m)
#pragma unroll
            for (int n = 0; n < 4; ++n) {
#pragma unroll
                for (int j = 0; j < 4; ++j)
                    __builtin_nontemporal_store(acc[m][n][j],
                        &C[(size_t)(crow + m * 16 + j) * N + ccol + n * 16]);
            }

        if (i + 1 < cnt) {
            int t1 = t0 + 1;
            int rp1 = t1 % mtiles, cp1 = t1 / mtiles;
            prolog(A + (size_t)rp1 * 256 * K, Bt + (size_t)cp1 * 256 * K);
            WAIT_VM0();
            BAR();
        }
    }
#undef MFMA_QUAD
}

// ---------------- flash attention ----------------
__global__ __launch_bounds__(256) void k_attn(const short* __restrict__ q,
                                              const short* __restrict__ k,
                                              const short* __restrict__ vT,
                                              short* __restrict__ out) {
    int qt = blockIdx.x, head = blockIdx.y, b = blockIdx.z;
    int qbase = qt * 64;
    __shared__ short Qs[64][72];
    __shared__ short Ps[4][16][72];
    int tid = threadIdx.x, lane = tid & 63, w = tid >> 6;
    int lr = lane & 15, lg4 = (lane >> 4) * 4, lk8 = (lane >> 4) * 8;

#pragma unroll
    for (int c = 0; c < 2; ++c) {
        int chunk = tid + 256 * c;
        int row = chunk >> 3, h8 = (chunk & 7) * 8;
        *(short8*)&Qs[row][h8] =
            *(const short8*)&q[(size_t)(b * T_ + qbase + row) * H_ + head * HD_ + h8];
    }
    __syncthreads();

    short8 qf[2];
    qf[0] = *(short8*)&Qs[w * 16 + lr][lk8];
    qf[1] = *(short8*)&Qs[w * 16 + lr][32 + lk8];

    f32x4 o[4] = {};
    float m[4] = {-1e30f, -1e30f, -1e30f, -1e30f};
    float lsum[4] = {0.f, 0.f, 0.f, 0.f};

    for (int kt = 0; kt <= qt; ++kt) {
        int kb = kt * 64;
        f32x4 s[4] = {};
#pragma unroll
        for (int ks = 0; ks < 2; ++ks) {
#pragma unroll
            for (int f = 0; f < 4; ++f) {
                short8 kf = *(const short8*)&k[(size_t)(b * T_ + kb + f * 16 + lr) * H_ +
                                               head * HD_ + ks * 32 + lk8];
                s[f] = __builtin_amdgcn_mfma_f32_16x16x32_bf16(qf[ks], kf, s[f], 0, 0, 0);
            }
        }
        if (kt == qt) {
#pragma unroll
            for (int f = 0; f < 4; ++f) {
                int key = kb + f * 16 + lr;
#pragma unroll
                for (int j = 0; j < 4; ++j) {
                    int qrow = qbase + w * 16 + lg4 + j;
                    if (key > qrow) s[f][j] = -1e30f;
                }
            }
        }
#pragma unroll
        for (int j = 0; j < 4; ++j) {
            float mx = fmaxf(fmaxf(s[0][j], s[1][j]), fmaxf(s[2][j], s[3][j]));
#pragma unroll
            for (int off = 1; off < 16; off <<= 1) mx = fmaxf(mx, __shfl_xor(mx, off, 64));
            float mnew = fmaxf(m[j], mx);
            float sc = __expf(m[j] - mnew);
            m[j] = mnew;
            float rs = 0.f;
#pragma unroll
            for (int f = 0; f < 4; ++f) {
                float p = __expf(s[f][j] - mnew);
                s[f][j] = p;
                rs += p;
            }
#pragma unroll
            for (int off = 1; off < 16; off <<= 1) rs += __shfl_xor(rs, off, 64);
            lsum[j] = lsum[j] * sc + rs;
#pragma unroll
            for (int f = 0; f < 4; ++f) o[f][j] *= sc;
#pragma unroll
            for (int f = 0; f < 4; ++f) Ps[w][lg4 + j][f * 16 + lr] = f2bf(s[f][j]);
        }
#pragma unroll
        for (int ks2 = 0; ks2 < 2; ++ks2) {
            short8 pf = *(short8*)&Ps[w][lr][ks2 * 32 + lk8];
            __builtin_amdgcn_s_setprio(1);
#pragma unroll
            for (int f = 0; f < 4; ++f) {
                short8 vf = *(const short8*)&vT[((size_t)(b * HEADS_ + head) * HD_ + f * 16 + lr) * T_ +
                                                kb + ks2 * 32 + lk8];
                o[f] = __builtin_amdgcn_mfma_f32_16x16x32_bf16(pf, vf, o[f], 0, 0, 0);
            }
            __builtin_amdgcn_s_setprio(0);
        }
    }
#pragma unroll
    for (int f = 0; f < 4; ++f)
#pragma unroll
        for (int j = 0; j < 4; ++j) {
            float val = o[f][j] / lsum[j];
            out[(size_t)(b * T_ + qbase + w * 16 + lg4 + j) * H_ + head * HD_ + f * 16 + lr] =
                f2bf(val);
        }
}

// ---------------- launch ----------------
extern "C" void kernel_launch(void* const* d_in, const int* in_sizes, int n_in,
                              void* d_out, int out_size, void* d_ws, size_t ws_size,
                              hipStream_t stream) {
    const float* prefix = (const float*)d_in[0];
    const int* ids = (const int*)d_in[1];
    const float* emb = (const float*)d_in[2];
    const float* Wq = (const float*)d_in[3];
    const float* Wk = (const float*)d_in[4];
    const float* Wv = (const float*)d_in[5];
    const float* Wo = (const float*)d_in[6];
    const float* g1 = (const float*)d_in[7];
    const float* b1 = (const float*)d_in[8];
    const float* g2 = (const float*)d_in[9];
    const float* b2 = (const float*)d_in[10];
    const float* W1 = (const float*)d_in[11];
    const float* bm1 = (const float*)d_in[12];
    const float* W2 = (const float*)d_in[13];
    const float* bm2 = (const float*)d_in[14];
    const float* gf = (const float*)d_in[15];
    const float* bf = (const float*)d_in[16];
    const float* Whead = (const float*)d_in[17];
    float* out = (float*)d_out;

    char* wsp = (char*)d_ws;
    float* x = (float*)wsp;   wsp += (size_t)BT_ * H_ * 4;
    float* p = (float*)wsp;   wsp += (size_t)4 * BT_ * H_ * 4;   // split-K x4 slabs
    short* h = (short*)wsp;   wsp += (size_t)BT_ * H_ * 2;
    short* qb = (short*)wsp;  wsp += (size_t)BT_ * H_ * 2;
    short* kb = (short*)wsp;  wsp += (size_t)BT_ * H_ * 2;
    short* vT = (short*)wsp;  wsp += (size_t)BT_ * H_ * 2;
    short* ao = (short*)wsp;  wsp += (size_t)BT_ * H_ * 2;
    short* mid = (short*)wsp; wsp += (size_t)BT_ * F_ * 2;
    short* WqkvT = (short*)wsp; wsp += (size_t)NL_ * 3 * H_ * H_ * 2;
    short* WoT = (short*)wsp;   wsp += (size_t)NL_ * H_ * H_ * 2;
    short* W1T = (short*)wsp;   wsp += (size_t)NL_ * H_ * F_ * 2;
    short* W2T = (short*)wsp;   wsp += (size_t)NL_ * F_ * H_ * 2;
    short* WhT = (short*)wsp;   wsp += (size_t)H_ * V_ * 2;

    dim3 blk(256);
    k_cvt_all<<<dim3(56576), blk, 0, stream>>>(Wq, Wk, Wv, Wo, W1, W2, Whead,
                                               WqkvT, WoT, W1T, W2T, WhT);
    k_embed_ln<<<BT_, blk, 0, stream>>>(prefix, ids, emb, g1, b1, x, h);
    for (int l = 0; l < NL_; ++l) {
        size_t o1 = (size_t)l * H_ * H_;
        size_t oq = (size_t)l * 3 * H_ * H_;
        size_t o2 = (size_t)l * H_ * F_;
        k_gemm<3, false, false, 1><<<dim3(576), blk, 0, stream>>>(
            h, WqkvT + oq, nullptr, qb, kb, vT, BT_, 3 * H_, H_, 1.f);
        k_attn<<<dim3(T_ / 64, HEADS_, B_), blk, 0, stream>>>(qb, kb, vT, ao);
        // Wo: split-K x4 -> p slabs (768 blocks = 3/CU); combine in k_add_ln
        k_gemm<0, false, false, 4><<<dim3(768), blk, 0, stream>>>(
            ao, WoT + o1, nullptr, p, nullptr, nullptr, BT_, H_, H_, 1.f);
        k_add_ln<<<BT_, blk, 0, stream>>>(x, p, g2 + l * H_, b2 + l * H_, h);
        k_gemm<1, true, true, 1><<<dim3(768), blk, 0, stream>>>(
            h, W1T + o2, bm1 + (size_t)l * F_, mid, nullptr, nullptr, BT_, F_, H_, 1.f);
        // W2: split-K x4 -> p slabs
        k_gemm<0, true, false, 4><<<dim3(768), blk, 0, stream>>>(
            mid, W2T + o2, bm2 + (size_t)l * H_, p, nullptr, nullptr, BT_, H_, F_, 1.f);
        const float* gn = (l + 1 < NL_) ? g1 + (l + 1) * H_ : gf;
        const float* bn = (l + 1 < NL_) ? b1 + (l + 1) * H_ : bf;
        k_add_ln<<<BT_, blk, 0, stream>>>(x, p, gn, bn, h);
    }
    // head GEMM: persistent 8-phase kernel, grid MUST be 256 (chunk math)
    k_gemm8<<<dim3(256), dim3(512), 0, stream>>>(h, WhT, out, BT_, V_, H_);
}